// Round 14
// baseline (3469.885 us; speedup 1.0000x reference)
//
#include <hip/hip_runtime.h>
#include <hip/hip_fp16.h>
#include <cmath>

typedef _Float16 h2 __attribute__((ext_vector_type(2)));
typedef _Float16 f16x8 __attribute__((ext_vector_type(8)));
typedef float f32x4 __attribute__((ext_vector_type(4)));

#define MFMA16 __builtin_amdgcn_mfma_f32_16x16x32_f16

#if defined(__has_builtin)
#if __has_builtin(__builtin_amdgcn_fdot2)
#define HAS_FDOT2 1
#endif
#endif

__device__ __forceinline__ float fdot2f(h2 a, h2 b, float c) {
#ifdef HAS_FDOT2
    return __builtin_amdgcn_fdot2(a, b, c, false);
#else
    c = fmaf((float)a[0], (float)b[0], c);
    return fmaf((float)a[1], (float)b[1], c);
#endif
}

__device__ __forceinline__ float sigm(float x) { return 1.0f / (1.0f + expf(-x)); }
__device__ __forceinline__ unsigned short f16b(float x) {
    _Float16 h = (_Float16)x; return __builtin_bit_cast(unsigned short, h);
}

// 16 dot2s for one (weight float4, x float4) pair; accumulates A0..A3 (4 rows x 4 cols)
#define DOT16(wf, xf) do { \
    h2 w0_ = __builtin_bit_cast(h2, (wf).x), w1_ = __builtin_bit_cast(h2, (wf).y); \
    h2 w2_ = __builtin_bit_cast(h2, (wf).z), w3_ = __builtin_bit_cast(h2, (wf).w); \
    h2 x0_ = __builtin_bit_cast(h2, (xf).x), x1_ = __builtin_bit_cast(h2, (xf).y); \
    h2 x2_ = __builtin_bit_cast(h2, (xf).z), x3_ = __builtin_bit_cast(h2, (xf).w); \
    A0.x = fdot2f(x0_, w0_, A0.x); A0.y = fdot2f(x0_, w1_, A0.y); \
    A0.z = fdot2f(x0_, w2_, A0.z); A0.w = fdot2f(x0_, w3_, A0.w); \
    A1.x = fdot2f(x1_, w0_, A1.x); A1.y = fdot2f(x1_, w1_, A1.y); \
    A1.z = fdot2f(x1_, w2_, A1.z); A1.w = fdot2f(x1_, w3_, A1.w); \
    A2.x = fdot2f(x2_, w0_, A2.x); A2.y = fdot2f(x2_, w1_, A2.y); \
    A2.z = fdot2f(x2_, w2_, A2.z); A2.w = fdot2f(x2_, w3_, A2.w); \
    A3.x = fdot2f(x3_, w0_, A3.x); A3.y = fdot2f(x3_, w1_, A3.y); \
    A3.z = fdot2f(x3_, w2_, A3.z); A3.w = fdot2f(x3_, w3_, A3.w); \
} while (0)

// ---- weight conversion: fp32 -> k-pair-packed f16 -------------------------------
__global__ __launch_bounds__(256) void convert_weights(
    const float* __restrict__ gate_k, const float* __restrict__ cand_k,
    float* __restrict__ gkh, float* __restrict__ ckh)
{
    int i = blockIdx.x * 256 + threadIdx.x;
    if (i < 8 * 256 * 512) {
        int col = i & 511, kp = (i >> 9) & 255, e2 = i >> 17;
        const float* src = gate_k + ((size_t)e2 * 512 + 2 * kp) * 512 + col;
        h2 v; v[0] = (_Float16)src[0]; v[1] = (_Float16)src[512];
        gkh[i] = __builtin_bit_cast(float, v);
    }
    if (i < 8 * 256 * 256) {
        int col = i & 255, kp = (i >> 8) & 255, e2 = i >> 16;
        const float* src = cand_k + ((size_t)e2 * 512 + 2 * kp) * 256 + col;
        h2 v; v[0] = (_Float16)src[0]; v[1] = (_Float16)src[256];
        ckh[i] = __builtin_bit_cast(float, v);
    }
}

// ---- Wprod pack into per-lane MFMA B-fragment layout ----------------------------
__global__ __launch_bounds__(256) void conv_wprod(const float* __restrict__ w1,
                                                  f16x8* __restrict__ wB)
{
    int i = blockIdx.x * 256 + threadIdx.x;   // [kt 32][nt 64][l 64]
    int l = i & 63, nt = (i >> 6) & 63, kt = i >> 12;
    int k0 = kt*32 + ((l >> 4) << 3);
    int n  = (nt << 4) + (l & 15);
    const float* src = w1 + (size_t)(2049 + k0) * 1024 + n;
    f16x8 v;
    #pragma unroll
    for (int j = 0; j < 8; ++j) v[j] = (_Float16)src[(size_t)j * 1024];
    wB[i] = v;
}

// ---- GRU hot loops (f16 dot2, 2-deep software-pipelined weight loads) -----------
// in0f layout: f16 element (k, row) at  (k>>1)*8 + row*2 + (k&1)
__device__ __forceinline__ void gate_partial_h(
    const _Float16* in0f, float* pbuf, const float* __restrict__ gk, int tid)
{
    int cg = tid & 127, q = tid >> 7;
    int c0 = cg * 4;
    const float* gp = gk + (size_t)(q * 32) * 512 + c0;
    const _Float16* xp = in0f + q * 32 * 8;
    float4 A0 = {0.f,0.f,0.f,0.f}, A1 = {0.f,0.f,0.f,0.f};
    float4 A2 = {0.f,0.f,0.f,0.f}, A3 = {0.f,0.f,0.f,0.f};
    float4 wb[4], xb[4], wn[4], xn[4];
    #pragma unroll
    for (int j = 0; j < 4; ++j) {
        wb[j] = *(const float4*)(gp + (size_t)j * 512);
        xb[j] = *(const float4*)(xp + j * 8);
    }
    #pragma unroll
    for (int b = 0; b < 8; ++b) {
        if (b < 7) {
            #pragma unroll
            for (int j = 0; j < 4; ++j) {
                wn[j] = *(const float4*)(gp + (size_t)((b + 1) * 4 + j) * 512);
                xn[j] = *(const float4*)(xp + ((b + 1) * 4 + j) * 8);
            }
        }
        #pragma unroll
        for (int j = 0; j < 4; ++j) DOT16(wb[j], xb[j]);
        if (b < 7) {
            #pragma unroll
            for (int j = 0; j < 4; ++j) { wb[j] = wn[j]; xb[j] = xn[j]; }
        }
    }
    *(float4*)&pbuf[(q * 4 + 0) * 512 + c0] = A0;
    *(float4*)&pbuf[(q * 4 + 1) * 512 + c0] = A1;
    *(float4*)&pbuf[(q * 4 + 2) * 512 + c0] = A2;
    *(float4*)&pbuf[(q * 4 + 3) * 512 + c0] = A3;
}

__device__ __forceinline__ void cand_partial_h(
    const _Float16* in0f, float* pbuf, const float* __restrict__ ck, int tid)
{
    int cg = tid & 63, q = tid >> 6;
    int c0 = cg * 4;
    const float* cp = ck + (size_t)(q * 16) * 256 + c0;
    const _Float16* xp = in0f + q * 16 * 8;
    float4 A0 = {0.f,0.f,0.f,0.f}, A1 = {0.f,0.f,0.f,0.f};
    float4 A2 = {0.f,0.f,0.f,0.f}, A3 = {0.f,0.f,0.f,0.f};
    float4 wb[4], xb[4], wn[4], xn[4];
    #pragma unroll
    for (int j = 0; j < 4; ++j) {
        wb[j] = *(const float4*)(cp + (size_t)j * 256);
        xb[j] = *(const float4*)(xp + j * 8);
    }
    #pragma unroll
    for (int b = 0; b < 4; ++b) {
        if (b < 3) {
            #pragma unroll
            for (int j = 0; j < 4; ++j) {
                wn[j] = *(const float4*)(cp + (size_t)((b + 1) * 4 + j) * 256);
                xn[j] = *(const float4*)(xp + ((b + 1) * 4 + j) * 8);
            }
        }
        #pragma unroll
        for (int j = 0; j < 4; ++j) DOT16(wb[j], xb[j]);
        if (b < 3) {
            #pragma unroll
            for (int j = 0; j < 4; ++j) { wb[j] = wn[j]; xb[j] = xn[j]; }
        }
    }
    *(float4*)&pbuf[(q * 4 + 0) * 256 + c0] = A0;
    *(float4*)&pbuf[(q * 4 + 1) * 256 + c0] = A1;
    *(float4*)&pbuf[(q * 4 + 2) * 256 + c0] = A2;
    *(float4*)&pbuf[(q * 4 + 3) * 256 + c0] = A3;
}

// grid = 128 blocks x 1024 threads; block = (encoder, 4-row chunk), fully
// workgroup-local recurrence; f16 weights, fp32 h state/partials.
__global__ __launch_bounds__(1024, 4) void gru_encode(
    const int* __restrict__ iq, const int* __restrict__ ir,
    const int* __restrict__ ql, const int* __restrict__ rl,
    const float* __restrict__ emb,
    const float* __restrict__ gkh, const float* __restrict__ gate_b,
    const float* __restrict__ ckh, const float* __restrict__ cand_b,
    float* __restrict__ Qo, float* __restrict__ Ro)
{
    int bid = blockIdx.x;
    int xcd = bid & 7;
    int enc = xcd >> 1;
    int chunk = (xcd & 1) * 16 + (bid >> 3);
    int b0 = chunk * 4;
    int tid = threadIdx.x;
    int c = tid & 255, r = tid >> 8;

    const int* toks = (enc < 2) ? iq : ir;
    const int* lens = (enc < 2) ? ql : rl;
    const bool bw = (enc & 1);

    const float* gk1 = gkh + (size_t)(enc * 2 + 0) * 131072;
    const float* gk2 = gkh + (size_t)(enc * 2 + 1) * 131072;
    const float* gb1 = gate_b + (enc * 2 + 0) * 512;
    const float* gb2 = gate_b + (enc * 2 + 1) * 512;
    const float* ck1 = ckh + (size_t)(enc * 2 + 0) * 65536;
    const float* ck2 = ckh + (size_t)(enc * 2 + 1) * 65536;
    const float* cb1 = cand_b + (enc * 2 + 0) * 256;
    const float* cb2 = cand_b + (enc * 2 + 1) * 256;

    __shared__ __align__(16) _Float16 in0f[256 * 8];   // 4KB  [kp][row*2+(k&1)]
    __shared__ float pbuf[16384];                      // 64KB partials
    __shared__ float h1rt[4][256];
    __shared__ float h2rt[4][256];
    __shared__ float gzt[4][256];
    __shared__ int tok_s[4];
    __shared__ int len_s[4];

    h1rt[r][c] = 0.f;
    h2rt[r][c] = 0.f;
    if (tid < 4) len_s[tid] = lens[b0 + tid];
    __syncthreads();
    int maxlen = max(max(len_s[0], len_s[1]), max(len_s[2], len_s[3]));
    if (tid < 4) {
        int len = len_s[tid];
        tok_s[tid] = toks[(b0 + tid) * 64 + (bw ? (len - 1) : 0)];
    }
    __syncthreads();

    for (int t = 0; t < maxlen; ++t) {
        // FILL: in0f = [x_t ; h1] as f16 pairs (pair-per-thread, b32 writes)
        if (tid < 512) {
            int kp = tid >> 2, rr = tid & 3;
            float2 xv = *(const float2*)(emb + (size_t)tok_s[rr] * 256 + 2 * kp);
            h2 v; v[0] = (_Float16)xv.x; v[1] = (_Float16)xv.y;
            *(float*)(in0f + kp * 8 + rr * 2) = __builtin_bit_cast(float, v);
        } else {
            int m = (tid - 512) >> 2, rr = tid & 3;
            h2 v; v[0] = (_Float16)h1rt[rr][2 * m]; v[1] = (_Float16)h1rt[rr][2 * m + 1];
            *(float*)(in0f + (128 + m) * 8 + rr * 2) = __builtin_bit_cast(float, v);
        }
        __syncthreads();

        // ---- layer 1 ----
        gate_partial_h(in0f, pbuf, gk1, tid);
        __syncthreads();
        {
            float s0 = gb1[c], s1 = gb1[256 + c];
            #pragma unroll
            for (int q = 0; q < 8; ++q) {
                s0 += pbuf[(q * 4 + r) * 512 + c];
                s1 += pbuf[(q * 4 + r) * 512 + c + 256];
            }
            float rh = sigm(s0) * h1rt[r][c];
            gzt[r][c] = sigm(s1);
            in0f[((256 + c) >> 1) * 8 + r * 2 + (c & 1)] = (_Float16)rh;
        }
        __syncthreads();
        cand_partial_h(in0f, pbuf, ck1, tid);
        __syncthreads();
        {
            float s = cb1[c];
            #pragma unroll
            for (int q = 0; q < 16; ++q) s += pbuf[(q * 4 + r) * 256 + c];
            float cv = tanhf(s);
            float z = gzt[r][c];
            float hn = fmaf(z, h1rt[r][c] - cv, cv);
            if (t < len_s[r]) h1rt[r][c] = hn;
            in0f[(c >> 1) * 8 + r * 2 + (c & 1)]         = (_Float16)hn;
            in0f[((256 + c) >> 1) * 8 + r * 2 + (c & 1)] = (_Float16)h2rt[r][c];
        }
        __syncthreads();

        // ---- layer 2 ----
        gate_partial_h(in0f, pbuf, gk2, tid);
        __syncthreads();
        {
            float s0 = gb2[c], s1 = gb2[256 + c];
            #pragma unroll
            for (int q = 0; q < 8; ++q) {
                s0 += pbuf[(q * 4 + r) * 512 + c];
                s1 += pbuf[(q * 4 + r) * 512 + c + 256];
            }
            float rh = sigm(s0) * h2rt[r][c];
            gzt[r][c] = sigm(s1);
            in0f[((256 + c) >> 1) * 8 + r * 2 + (c & 1)] = (_Float16)rh;
        }
        __syncthreads();
        cand_partial_h(in0f, pbuf, ck2, tid);
        __syncthreads();
        {
            float s = cb2[c];
            #pragma unroll
            for (int q = 0; q < 16; ++q) s += pbuf[(q * 4 + r) * 256 + c];
            float cv = tanhf(s);
            float z = gzt[r][c];
            float hn = fmaf(z, h2rt[r][c] - cv, cv);
            if (t < len_s[r]) h2rt[r][c] = hn;
        }
        if (tid < 4) {   // token prefetch for t+1
            int t2 = t + 1;
            if (t2 < 64) {
                int len = len_s[tid];
                int tt = bw ? ((t2 < len) ? (len - 1 - t2) : t2) : t2;
                tok_s[tid] = toks[(b0 + tid) * 64 + tt];
            }
        }
        __syncthreads();
    }

    float* outp = (enc < 2) ? Qo : Ro;
    int off = (enc & 1) ? 512 : 0;
    outp[(size_t)(b0 + r) * 1024 + off + c]       = h1rt[r][c];
    outp[(size_t)(b0 + r) * 1024 + off + 256 + c] = h2rt[r][c];
}

// ---------------- dist / ab (unchanged fp32) --------------------------------------
__global__ void dist_kernel(const float* __restrict__ Q, const float* __restrict__ R,
                            float* __restrict__ dist)
{
    int gidx = blockIdx.x * 256 + threadIdx.x;
    int i = gidx >> 7, j = gidx & 127;
    const float4* q4 = (const float4*)(Q + (size_t)i * 1024);
    const float4* r4 = (const float4*)(R + (size_t)j * 1024);
    float acc = 0.f;
    for (int k = 0; k < 256; ++k) {
        float4 a = q4[k], b = r4[k];
        acc += a.x * b.x + a.y * b.y + a.z * b.z + a.w * b.w;
    }
    dist[gidx] = acc;
}

__global__ __launch_bounds__(256) void ab_kernel(
    const float* __restrict__ Q, const float* __restrict__ R,
    const float* __restrict__ w1, float* __restrict__ A, float* __restrict__ Bv)
{
    int nb = blockIdx.x, rb = blockIdx.y, mat = blockIdx.z;
    int tid = threadIdx.x;
    int n = nb * 256 + tid;
    int r0 = rb * 16;
    const float* src   = mat ? R : Q;
    const float* wmain = mat ? (w1 + (size_t)3073 * 1024) : w1;
    const float* wdiff = w1 + (size_t)1025 * 1024;
    float sgn = mat ? -1.f : 1.f;

    __shared__ float Qs[16][64];
    float acc[16];
    #pragma unroll
    for (int r = 0; r < 16; ++r) acc[r] = 0.f;

    for (int k0 = 0; k0 < 1024; k0 += 64) {
        __syncthreads();
        #pragma unroll
        for (int s = 0; s < 4; ++s) {
            int e = s * 256 + tid;
            int r = e >> 6, kk = e & 63;
            Qs[r][kk] = src[(size_t)(r0 + r) * 1024 + k0 + kk];
        }
        __syncthreads();
        for (int kk = 0; kk < 64; ++kk) {
            size_t row = (size_t)(k0 + kk) * 1024 + n;
            float w = wmain[row] + sgn * wdiff[row];
            #pragma unroll
            for (int r = 0; r < 16; ++r)
                acc[r] = fmaf(Qs[r][kk], w, acc[r]);
        }
    }
    float* dst = mat ? Bv : A;
    #pragma unroll
    for (int r = 0; r < 16; ++r)
        dst[(size_t)(r0 + r) * 1024 + n] = acc[r];
}

// ---------------- pair GEMM: 128x128 tile MFMA, fused epilogue --------------------
__global__ __launch_bounds__(512, 2) void pair_gemm(
    const float* __restrict__ Q, const float* __restrict__ R,
    const float* __restrict__ Aq, const float* __restrict__ Bv,
    const float* __restrict__ dist,
    const int* __restrict__ nqi, const int* __restrict__ nri,
    const f16x8* __restrict__ wB,
    const float* __restrict__ w1, const float* __restrict__ b1,
    const float* __restrict__ w2, float* __restrict__ partial)
{
    int bm = blockIdx.x, bn = blockIdx.y;
    int tid = threadIdx.x, w = tid >> 6, l = tid & 63;
    __shared__ __align__(16) unsigned short As[4096];    // [128 rows][32 k] f16, k-octet ^ (row&3)
    __shared__ float red[2048];                          // [8 waves][128 rows][2]
    __shared__ int qis[128], ris[128];
    __shared__ float dsv[128];
    if (tid < 128) {
        int p = bm*128 + tid;
        int qi = (p < 128) ? p : nqi[p-128];
        int ri = (p < 128) ? p : nri[p-128];
        qis[tid] = qi; ris[tid] = ri; dsv[tid] = dist[qi*128 + ri];
    }
    __syncthreads();

    int srow = tid & 127, skg = tid >> 7;
    const float* qrow = Q + (size_t)qis[srow]*1024 + skg*8;
    const float* rrow = R + (size_t)ris[srow]*1024 + skg*8;

    float4 qa = *(const float4*)(qrow);
    float4 qb = *(const float4*)(qrow + 4);
    float4 ra = *(const float4*)(rrow);
    float4 rb = *(const float4*)(rrow + 4);

    f32x4 acc[8];
    #pragma unroll
    for (int m = 0; m < 8; ++m) acc[m] = (f32x4){0.f,0.f,0.f,0.f};

    for (int kt = 0; kt < 32; ++kt) {
        f16x8 prod;
        prod[0]=(_Float16)(qa.x*ra.x); prod[1]=(_Float16)(qa.y*ra.y);
        prod[2]=(_Float16)(qa.z*ra.z); prod[3]=(_Float16)(qa.w*ra.w);
        prod[4]=(_Float16)(qb.x*rb.x); prod[5]=(_Float16)(qb.y*rb.y);
        prod[6]=(_Float16)(qb.z*rb.z); prod[7]=(_Float16)(qb.w*rb.w);
        __syncthreads();
        ((f16x8*)As)[srow*4 + (skg ^ (srow & 3))] = prod;
        __syncthreads();
        if (kt + 1 < 32) {
            qa = *(const float4*)(qrow + (kt+1)*32);
            qb = *(const float4*)(qrow + (kt+1)*32 + 4);
            ra = *(const float4*)(rrow + (kt+1)*32);
            rb = *(const float4*)(rrow + (kt+1)*32 + 4);
        }
        f16x8 bf = wB[((size_t)kt*64 + bn*8 + w)*64 + l];
        #pragma unroll
        for (int mt = 0; mt < 8; ++mt) {
            f16x8 af = ((const f16x8*)As)[(mt*16 + (l & 15))*4 + ((l >> 4) ^ (l & 3))];
            acc[mt] = MFMA16(af, bf, acc[mt], 0, 0, 0);
        }
    }

    int col = bn*128 + w*16 + (l & 15);
    float wd  = w1[(size_t)1024*1024 + col];
    float b1v = b1[col];
    float w20 = w2[col*2], w21 = w2[col*2 + 1];
    #pragma unroll
    for (int mt = 0; mt < 8; ++mt) {
        float po0[4], po1[4];
        #pragma unroll
        for (int j = 0; j < 4; ++j) {
            int lr = mt*16 + (l >> 4)*4 + j;
            float h = acc[mt][j]
                    + Aq[(size_t)qis[lr]*1024 + col]
                    + Bv[(size_t)ris[lr]*1024 + col]
                    + dsv[lr]*wd + b1v;
            h = fmaxf(h, 0.f);
            po0[j] = h * w20; po1[j] = h * w21;
        }
        #pragma unroll
        for (int s = 1; s < 16; s <<= 1) {
            #pragma unroll
            for (int j = 0; j < 4; ++j) {
                po0[j] += __shfl_xor(po0[j], s, 64);
                po1[j] += __shfl_xor(po1[j], s, 64);
            }
        }
        if ((l & 15) == 0) {
            #pragma unroll
            for (int j = 0; j < 4; ++j) {
                int row = mt*16 + (l >> 4)*4 + j;
                red[(w*128 + row)*2 + 0] = po0[j];
                red[(w*128 + row)*2 + 1] = po1[j];
            }
        }
    }
    __syncthreads();
    if (tid < 256) {
        int row = tid >> 1, cc = tid & 1;
        float s = 0.f;
        #pragma unroll
        for (int ww = 0; ww < 8; ++ww) s += red[(ww*128 + row)*2 + cc];
        partial[((size_t)bn*16384 + bm*128 + row)*2 + cc] = s;
    }
}

__global__ void final_reduce(const float* __restrict__ partial,
                             const float* __restrict__ b2, float* __restrict__ out)
{
    int gidx = blockIdx.x * 256 + threadIdx.x;
    int p = gidx >> 1, c = gidx & 1;
    float s = b2[c];
    #pragma unroll
    for (int nt = 0; nt < 8; ++nt)
        s += partial[((size_t)nt * 16384 + p) * 2 + c];
    out[gidx] = s;
}

extern "C" void kernel_launch(void* const* d_in, const int* in_sizes, int n_in,
                              void* d_out, int out_size, void* d_ws, size_t ws_size,
                              hipStream_t stream) {
    const int*   iq     = (const int*)d_in[0];
    const int*   ir     = (const int*)d_in[1];
    const int*   ql     = (const int*)d_in[2];
    const int*   rl     = (const int*)d_in[3];
    const int*   nqi    = (const int*)d_in[4];
    const int*   nri    = (const int*)d_in[5];
    const float* emb    = (const float*)d_in[6];
    const float* gate_k = (const float*)d_in[7];
    const float* gate_b = (const float*)d_in[8];
    const float* cand_k = (const float*)d_in[9];
    const float* cand_b = (const float*)d_in[10];
    const float* w1     = (const float*)d_in[11];
    const float* b1     = (const float*)d_in[12];
    const float* w2     = (const float*)d_in[13];
    const float* b2     = (const float*)d_in[14];
    float* out = (float*)d_out;
    float* ws  = (float*)d_ws;

    float* Q       = ws;                  // 131072
    float* R       = ws + 131072;         // 131072
    float* A       = ws + 262144;         // 131072
    float* Bv      = ws + 393216;         // 131072
    float* dist    = ws + 524288;         // 16384
    float* partial = ws + 540672;         // 262144
    float* gkh     = ws + 1064960;        // 8*256*512
    float* ckh     = ws + 2113536;        // 8*256*256
    f16x8* wB      = (f16x8*)(ws + 2637824);  // ends 3162112 floats

    convert_weights<<<4096, 256, 0, stream>>>(gate_k, cand_k, gkh, ckh);
    conv_wprod<<<512, 256, 0, stream>>>(w1, wB);
    gru_encode<<<128, 1024, 0, stream>>>(iq, ir, ql, rl, emb, gkh, gate_b,
                                         ckh, cand_b, Q, R);
    dist_kernel<<<64, 256, 0, stream>>>(Q, R, dist);
    ab_kernel<<<dim3(4, 8, 2), 256, 0, stream>>>(Q, R, w1, A, Bv);
    pair_gemm<<<dim3(128, 8), 512, 0, stream>>>(Q, R, A, Bv, dist, nqi, nri,
                                                wB, w1, b1, w2, partial);
    final_reduce<<<128, 256, 0, stream>>>(partial, b2, out);
}

// Round 15
// 1724.087 us; speedup vs baseline: 2.0126x; 2.0126x over previous
//
#include <hip/hip_runtime.h>
#include <hip/hip_fp16.h>
#include <cmath>

typedef _Float16 h2 __attribute__((ext_vector_type(2)));
typedef _Float16 f16x8 __attribute__((ext_vector_type(8)));
typedef float f32x4 __attribute__((ext_vector_type(4)));

#define MFMA16 __builtin_amdgcn_mfma_f32_16x16x32_f16

#if defined(__has_builtin)
#if __has_builtin(__builtin_amdgcn_fdot2)
#define HAS_FDOT2 1
#endif
#endif

__device__ __forceinline__ float fdot2f(h2 a, h2 b, float c) {
#ifdef HAS_FDOT2
    return __builtin_amdgcn_fdot2(a, b, c, false);
#else
    c = fmaf((float)a[0], (float)b[0], c);
    return fmaf((float)a[1], (float)b[1], c);
#endif
}

__device__ __forceinline__ float sigm(float x) { return 1.0f / (1.0f + expf(-x)); }
__device__ __forceinline__ unsigned short f16b(float x) {
    _Float16 h = (_Float16)x; return __builtin_bit_cast(unsigned short, h);
}

// ---- weight conversion: fp32 -> k-pair-packed f16 (round-4/12 proven) -----------
__global__ __launch_bounds__(256) void convert_weights(
    const float* __restrict__ gate_k, const float* __restrict__ cand_k,
    float* __restrict__ gkh, float* __restrict__ ckh)
{
    int i = blockIdx.x * 256 + threadIdx.x;
    if (i < 8 * 256 * 512) {
        int col = i & 511, kp = (i >> 9) & 255, e2 = i >> 17;
        const float* src = gate_k + ((size_t)e2 * 512 + 2 * kp) * 512 + col;
        h2 v; v[0] = (_Float16)src[0]; v[1] = (_Float16)src[512];
        gkh[i] = __builtin_bit_cast(float, v);
    }
    if (i < 8 * 256 * 256) {
        int col = i & 255, kp = (i >> 8) & 255, e2 = i >> 16;
        const float* src = cand_k + ((size_t)e2 * 512 + 2 * kp) * 256 + col;
        h2 v; v[0] = (_Float16)src[0]; v[1] = (_Float16)src[256];
        ckh[i] = __builtin_bit_cast(float, v);
    }
}

// ---- Wprod pack into per-lane MFMA B-fragment layout ----------------------------
__global__ __launch_bounds__(256) void conv_wprod(const float* __restrict__ w1,
                                                  f16x8* __restrict__ wB)
{
    int i = blockIdx.x * 256 + threadIdx.x;   // [kt 32][nt 64][l 64]
    int l = i & 63, nt = (i >> 6) & 63, kt = i >> 12;
    int k0 = kt*32 + ((l >> 4) << 3);
    int n  = (nt << 4) + (l & 15);
    const float* src = w1 + (size_t)(2049 + k0) * 1024 + n;
    f16x8 v;
    #pragma unroll
    for (int j = 0; j < 8; ++j) v[j] = (_Float16)src[(size_t)j * 1024];
    wB[i] = v;
}

// ---- GRU hot loops (f16 dot2; compiler-scheduled loads — DO NOT batch/pipeline:
// round-14 showed deep load batching flips L2 into streaming-evict, FETCH 18MB->3.8GB)
__device__ __forceinline__ void gate_partial_h(
    const _Float16* in0f, float* pbuf, const float* __restrict__ gk, int tid)
{
    int cg = tid & 127, q = tid >> 7;
    int c0 = cg * 4;
    const float* gp = gk + (size_t)(q * 32) * 512 + c0;
    const _Float16* xp = in0f + q * 32 * 8;
    float4 A0 = {0.f,0.f,0.f,0.f}, A1 = {0.f,0.f,0.f,0.f};
    float4 A2 = {0.f,0.f,0.f,0.f}, A3 = {0.f,0.f,0.f,0.f};
    #pragma unroll 8
    for (int i = 0; i < 32; ++i) {
        float4 wf = *(const float4*)(gp + (size_t)i * 512);
        float4 xf = *(const float4*)(xp + i * 8);
        h2 w0 = __builtin_bit_cast(h2, wf.x), w1 = __builtin_bit_cast(h2, wf.y);
        h2 w2 = __builtin_bit_cast(h2, wf.z), w3 = __builtin_bit_cast(h2, wf.w);
        h2 x0 = __builtin_bit_cast(h2, xf.x), x1 = __builtin_bit_cast(h2, xf.y);
        h2 x2 = __builtin_bit_cast(h2, xf.z), x3 = __builtin_bit_cast(h2, xf.w);
        A0.x = fdot2f(x0, w0, A0.x); A0.y = fdot2f(x0, w1, A0.y);
        A0.z = fdot2f(x0, w2, A0.z); A0.w = fdot2f(x0, w3, A0.w);
        A1.x = fdot2f(x1, w0, A1.x); A1.y = fdot2f(x1, w1, A1.y);
        A1.z = fdot2f(x1, w2, A1.z); A1.w = fdot2f(x1, w3, A1.w);
        A2.x = fdot2f(x2, w0, A2.x); A2.y = fdot2f(x2, w1, A2.y);
        A2.z = fdot2f(x2, w2, A2.z); A2.w = fdot2f(x2, w3, A2.w);
        A3.x = fdot2f(x3, w0, A3.x); A3.y = fdot2f(x3, w1, A3.y);
        A3.z = fdot2f(x3, w2, A3.z); A3.w = fdot2f(x3, w3, A3.w);
    }
    *(float4*)&pbuf[(q * 4 + 0) * 512 + c0] = A0;
    *(float4*)&pbuf[(q * 4 + 1) * 512 + c0] = A1;
    *(float4*)&pbuf[(q * 4 + 2) * 512 + c0] = A2;
    *(float4*)&pbuf[(q * 4 + 3) * 512 + c0] = A3;
}

__device__ __forceinline__ void cand_partial_h(
    const _Float16* in0f, float* pbuf, const float* __restrict__ ck, int tid)
{
    int cg = tid & 63, q = tid >> 6;
    int c0 = cg * 4;
    const float* cp = ck + (size_t)(q * 16) * 256 + c0;
    const _Float16* xp = in0f + q * 16 * 8;
    float4 A0 = {0.f,0.f,0.f,0.f}, A1 = {0.f,0.f,0.f,0.f};
    float4 A2 = {0.f,0.f,0.f,0.f}, A3 = {0.f,0.f,0.f,0.f};
    #pragma unroll 8
    for (int i = 0; i < 16; ++i) {
        float4 wf = *(const float4*)(cp + (size_t)i * 256);
        float4 xf = *(const float4*)(xp + i * 8);
        h2 w0 = __builtin_bit_cast(h2, wf.x), w1 = __builtin_bit_cast(h2, wf.y);
        h2 w2 = __builtin_bit_cast(h2, wf.z), w3 = __builtin_bit_cast(h2, wf.w);
        h2 x0 = __builtin_bit_cast(h2, xf.x), x1 = __builtin_bit_cast(h2, xf.y);
        h2 x2 = __builtin_bit_cast(h2, xf.z), x3 = __builtin_bit_cast(h2, xf.w);
        A0.x = fdot2f(x0, w0, A0.x); A0.y = fdot2f(x0, w1, A0.y);
        A0.z = fdot2f(x0, w2, A0.z); A0.w = fdot2f(x0, w3, A0.w);
        A1.x = fdot2f(x1, w0, A1.x); A1.y = fdot2f(x1, w1, A1.y);
        A1.z = fdot2f(x1, w2, A1.z); A1.w = fdot2f(x1, w3, A1.w);
        A2.x = fdot2f(x2, w0, A2.x); A2.y = fdot2f(x2, w1, A2.y);
        A2.z = fdot2f(x2, w2, A2.z); A2.w = fdot2f(x2, w3, A2.w);
        A3.x = fdot2f(x3, w0, A3.x); A3.y = fdot2f(x3, w1, A3.y);
        A3.z = fdot2f(x3, w2, A3.z); A3.w = fdot2f(x3, w3, A3.w);
    }
    *(float4*)&pbuf[(q * 4 + 0) * 256 + c0] = A0;
    *(float4*)&pbuf[(q * 4 + 1) * 256 + c0] = A1;
    *(float4*)&pbuf[(q * 4 + 2) * 256 + c0] = A2;
    *(float4*)&pbuf[(q * 4 + 3) * 256 + c0] = A3;
}

// grid = 128 blocks x 1024 threads; block = (encoder, 4-row chunk), fully
// workgroup-local recurrence; f16 weights, fp32 h state/partials. (round-12 exact)
__global__ __launch_bounds__(1024, 4) void gru_encode(
    const int* __restrict__ iq, const int* __restrict__ ir,
    const int* __restrict__ ql, const int* __restrict__ rl,
    const float* __restrict__ emb,
    const float* __restrict__ gkh, const float* __restrict__ gate_b,
    const float* __restrict__ ckh, const float* __restrict__ cand_b,
    float* __restrict__ Qo, float* __restrict__ Ro)
{
    int bid = blockIdx.x;
    int xcd = bid & 7;
    int enc = xcd >> 1;
    int chunk = (xcd & 1) * 16 + (bid >> 3);
    int b0 = chunk * 4;
    int tid = threadIdx.x;
    int c = tid & 255, r = tid >> 8;

    const int* toks = (enc < 2) ? iq : ir;
    const int* lens = (enc < 2) ? ql : rl;
    const bool bw = (enc & 1);

    const float* gk1 = gkh + (size_t)(enc * 2 + 0) * 131072;
    const float* gk2 = gkh + (size_t)(enc * 2 + 1) * 131072;
    const float* gb1 = gate_b + (enc * 2 + 0) * 512;
    const float* gb2 = gate_b + (enc * 2 + 1) * 512;
    const float* ck1 = ckh + (size_t)(enc * 2 + 0) * 65536;
    const float* ck2 = ckh + (size_t)(enc * 2 + 1) * 65536;
    const float* cb1 = cand_b + (enc * 2 + 0) * 256;
    const float* cb2 = cand_b + (enc * 2 + 1) * 256;

    __shared__ __align__(16) _Float16 in0f[256 * 8];   // 4KB  [kp][row*2+(k&1)]
    __shared__ float pbuf[16384];                      // 64KB partials
    __shared__ float h1rt[4][256];
    __shared__ float h2rt[4][256];
    __shared__ float gzt[4][256];
    __shared__ int tok_s[4];
    __shared__ int len_s[4];

    h1rt[r][c] = 0.f;
    h2rt[r][c] = 0.f;
    if (tid < 4) len_s[tid] = lens[b0 + tid];
    __syncthreads();
    int maxlen = max(max(len_s[0], len_s[1]), max(len_s[2], len_s[3]));
    if (tid < 4) {
        int len = len_s[tid];
        tok_s[tid] = toks[(b0 + tid) * 64 + (bw ? (len - 1) : 0)];
    }
    __syncthreads();

    for (int t = 0; t < maxlen; ++t) {
        // FILL: in0f = [x_t ; h1] as f16 pairs (pair-per-thread, b32 writes)
        if (tid < 512) {
            int kp = tid >> 2, rr = tid & 3;
            float2 xv = *(const float2*)(emb + (size_t)tok_s[rr] * 256 + 2 * kp);
            h2 v; v[0] = (_Float16)xv.x; v[1] = (_Float16)xv.y;
            *(float*)(in0f + kp * 8 + rr * 2) = __builtin_bit_cast(float, v);
        } else {
            int m = (tid - 512) >> 2, rr = tid & 3;
            h2 v; v[0] = (_Float16)h1rt[rr][2 * m]; v[1] = (_Float16)h1rt[rr][2 * m + 1];
            *(float*)(in0f + (128 + m) * 8 + rr * 2) = __builtin_bit_cast(float, v);
        }
        __syncthreads();

        // ---- layer 1 ----
        gate_partial_h(in0f, pbuf, gk1, tid);
        __syncthreads();
        {
            float s0 = gb1[c], s1 = gb1[256 + c];
            #pragma unroll
            for (int q = 0; q < 8; ++q) {
                s0 += pbuf[(q * 4 + r) * 512 + c];
                s1 += pbuf[(q * 4 + r) * 512 + c + 256];
            }
            float rh = sigm(s0) * h1rt[r][c];
            gzt[r][c] = sigm(s1);
            in0f[((256 + c) >> 1) * 8 + r * 2 + (c & 1)] = (_Float16)rh;
        }
        __syncthreads();
        cand_partial_h(in0f, pbuf, ck1, tid);
        __syncthreads();
        {
            float s = cb1[c];
            #pragma unroll
            for (int q = 0; q < 16; ++q) s += pbuf[(q * 4 + r) * 256 + c];
            float cv = tanhf(s);
            float z = gzt[r][c];
            float hn = fmaf(z, h1rt[r][c] - cv, cv);
            if (t < len_s[r]) h1rt[r][c] = hn;
            in0f[(c >> 1) * 8 + r * 2 + (c & 1)]         = (_Float16)hn;
            in0f[((256 + c) >> 1) * 8 + r * 2 + (c & 1)] = (_Float16)h2rt[r][c];
        }
        __syncthreads();

        // ---- layer 2 ----
        gate_partial_h(in0f, pbuf, gk2, tid);
        __syncthreads();
        {
            float s0 = gb2[c], s1 = gb2[256 + c];
            #pragma unroll
            for (int q = 0; q < 8; ++q) {
                s0 += pbuf[(q * 4 + r) * 512 + c];
                s1 += pbuf[(q * 4 + r) * 512 + c + 256];
            }
            float rh = sigm(s0) * h2rt[r][c];
            gzt[r][c] = sigm(s1);
            in0f[((256 + c) >> 1) * 8 + r * 2 + (c & 1)] = (_Float16)rh;
        }
        __syncthreads();
        cand_partial_h(in0f, pbuf, ck2, tid);
        __syncthreads();
        {
            float s = cb2[c];
            #pragma unroll
            for (int q = 0; q < 16; ++q) s += pbuf[(q * 4 + r) * 256 + c];
            float cv = tanhf(s);
            float z = gzt[r][c];
            float hn = fmaf(z, h2rt[r][c] - cv, cv);
            if (t < len_s[r]) h2rt[r][c] = hn;
        }
        if (tid < 4) {   // token prefetch for t+1
            int t2 = t + 1;
            if (t2 < 64) {
                int len = len_s[tid];
                int tt = bw ? ((t2 < len) ? (len - 1 - t2) : t2) : t2;
                tok_s[tid] = toks[(b0 + tid) * 64 + tt];
            }
        }
        __syncthreads();
    }

    float* outp = (enc < 2) ? Qo : Ro;
    int off = (enc & 1) ? 512 : 0;
    outp[(size_t)(b0 + r) * 1024 + off + c]       = h1rt[r][c];
    outp[(size_t)(b0 + r) * 1024 + off + 256 + c] = h2rt[r][c];
}

// ---------------- dist / ab (unchanged fp32) --------------------------------------
__global__ void dist_kernel(const float* __restrict__ Q, const float* __restrict__ R,
                            float* __restrict__ dist)
{
    int gidx = blockIdx.x * 256 + threadIdx.x;
    int i = gidx >> 7, j = gidx & 127;
    const float4* q4 = (const float4*)(Q + (size_t)i * 1024);
    const float4* r4 = (const float4*)(R + (size_t)j * 1024);
    float acc = 0.f;
    for (int k = 0; k < 256; ++k) {
        float4 a = q4[k], b = r4[k];
        acc += a.x * b.x + a.y * b.y + a.z * b.z + a.w * b.w;
    }
    dist[gidx] = acc;
}

__global__ __launch_bounds__(256) void ab_kernel(
    const float* __restrict__ Q, const float* __restrict__ R,
    const float* __restrict__ w1, float* __restrict__ A, float* __restrict__ Bv)
{
    int nb = blockIdx.x, rb = blockIdx.y, mat = blockIdx.z;
    int tid = threadIdx.x;
    int n = nb * 256 + tid;
    int r0 = rb * 16;
    const float* src   = mat ? R : Q;
    const float* wmain = mat ? (w1 + (size_t)3073 * 1024) : w1;
    const float* wdiff = w1 + (size_t)1025 * 1024;
    float sgn = mat ? -1.f : 1.f;

    __shared__ float Qs[16][64];
    float acc[16];
    #pragma unroll
    for (int r = 0; r < 16; ++r) acc[r] = 0.f;

    for (int k0 = 0; k0 < 1024; k0 += 64) {
        __syncthreads();
        #pragma unroll
        for (int s = 0; s < 4; ++s) {
            int e = s * 256 + tid;
            int r = e >> 6, kk = e & 63;
            Qs[r][kk] = src[(size_t)(r0 + r) * 1024 + k0 + kk];
        }
        __syncthreads();
        for (int kk = 0; kk < 64; ++kk) {
            size_t row = (size_t)(k0 + kk) * 1024 + n;
            float w = wmain[row] + sgn * wdiff[row];
            #pragma unroll
            for (int r = 0; r < 16; ++r)
                acc[r] = fmaf(Qs[r][kk], w, acc[r]);
        }
    }
    float* dst = mat ? Bv : A;
    #pragma unroll
    for (int r = 0; r < 16; ++r)
        dst[(size_t)(r0 + r) * 1024 + n] = acc[r];
}

// ---------------- pair GEMM: 128x128 tile MFMA, fused epilogue --------------------
__global__ __launch_bounds__(512, 2) void pair_gemm(
    const float* __restrict__ Q, const float* __restrict__ R,
    const float* __restrict__ Aq, const float* __restrict__ Bv,
    const float* __restrict__ dist,
    const int* __restrict__ nqi, const int* __restrict__ nri,
    const f16x8* __restrict__ wB,
    const float* __restrict__ w1, const float* __restrict__ b1,
    const float* __restrict__ w2, float* __restrict__ partial)
{
    int bm = blockIdx.x, bn = blockIdx.y;
    int tid = threadIdx.x, w = tid >> 6, l = tid & 63;
    __shared__ __align__(16) unsigned short As[4096];    // [128 rows][32 k] f16, k-octet ^ (row&3)
    __shared__ float red[2048];                          // [8 waves][128 rows][2]
    __shared__ int qis[128], ris[128];
    __shared__ float dsv[128];
    if (tid < 128) {
        int p = bm*128 + tid;
        int qi = (p < 128) ? p : nqi[p-128];
        int ri = (p < 128) ? p : nri[p-128];
        qis[tid] = qi; ris[tid] = ri; dsv[tid] = dist[qi*128 + ri];
    }
    __syncthreads();

    int srow = tid & 127, skg = tid >> 7;
    const float* qrow = Q + (size_t)qis[srow]*1024 + skg*8;
    const float* rrow = R + (size_t)ris[srow]*1024 + skg*8;

    float4 qa = *(const float4*)(qrow);
    float4 qb = *(const float4*)(qrow + 4);
    float4 ra = *(const float4*)(rrow);
    float4 rb = *(const float4*)(rrow + 4);

    f32x4 acc[8];
    #pragma unroll
    for (int m = 0; m < 8; ++m) acc[m] = (f32x4){0.f,0.f,0.f,0.f};

    for (int kt = 0; kt < 32; ++kt) {
        f16x8 prod;
        prod[0]=(_Float16)(qa.x*ra.x); prod[1]=(_Float16)(qa.y*ra.y);
        prod[2]=(_Float16)(qa.z*ra.z); prod[3]=(_Float16)(qa.w*ra.w);
        prod[4]=(_Float16)(qb.x*rb.x); prod[5]=(_Float16)(qb.y*rb.y);
        prod[6]=(_Float16)(qb.z*rb.z); prod[7]=(_Float16)(qb.w*rb.w);
        __syncthreads();
        ((f16x8*)As)[srow*4 + (skg ^ (srow & 3))] = prod;
        __syncthreads();
        if (kt + 1 < 32) {
            qa = *(const float4*)(qrow + (kt+1)*32);
            qb = *(const float4*)(qrow + (kt+1)*32 + 4);
            ra = *(const float4*)(rrow + (kt+1)*32);
            rb = *(const float4*)(rrow + (kt+1)*32 + 4);
        }
        f16x8 bf = wB[((size_t)kt*64 + bn*8 + w)*64 + l];
        #pragma unroll
        for (int mt = 0; mt < 8; ++mt) {
            f16x8 af = ((const f16x8*)As)[(mt*16 + (l & 15))*4 + ((l >> 4) ^ (l & 3))];
            acc[mt] = MFMA16(af, bf, acc[mt], 0, 0, 0);
        }
    }

    int col = bn*128 + w*16 + (l & 15);
    float wd  = w1[(size_t)1024*1024 + col];
    float b1v = b1[col];
    float w20 = w2[col*2], w21 = w2[col*2 + 1];
    #pragma unroll
    for (int mt = 0; mt < 8; ++mt) {
        float po0[4], po1[4];
        #pragma unroll
        for (int j = 0; j < 4; ++j) {
            int lr = mt*16 + (l >> 4)*4 + j;
            float h = acc[mt][j]
                    + Aq[(size_t)qis[lr]*1024 + col]
                    + Bv[(size_t)ris[lr]*1024 + col]
                    + dsv[lr]*wd + b1v;
            h = fmaxf(h, 0.f);
            po0[j] = h * w20; po1[j] = h * w21;
        }
        #pragma unroll
        for (int s = 1; s < 16; s <<= 1) {
            #pragma unroll
            for (int j = 0; j < 4; ++j) {
                po0[j] += __shfl_xor(po0[j], s, 64);
                po1[j] += __shfl_xor(po1[j], s, 64);
            }
        }
        if ((l & 15) == 0) {
            #pragma unroll
            for (int j = 0; j < 4; ++j) {
                int row = mt*16 + (l >> 4)*4 + j;
                red[(w*128 + row)*2 + 0] = po0[j];
                red[(w*128 + row)*2 + 1] = po1[j];
            }
        }
    }
    __syncthreads();
    if (tid < 256) {
        int row = tid >> 1, cc = tid & 1;
        float s = 0.f;
        #pragma unroll
        for (int ww = 0; ww < 8; ++ww) s += red[(ww*128 + row)*2 + cc];
        partial[((size_t)bn*16384 + bm*128 + row)*2 + cc] = s;
    }
}

__global__ void final_reduce(const float* __restrict__ partial,
                             const float* __restrict__ b2, float* __restrict__ out)
{
    int gidx = blockIdx.x * 256 + threadIdx.x;
    int p = gidx >> 1, c = gidx & 1;
    float s = b2[c];
    #pragma unroll
    for (int nt = 0; nt < 8; ++nt)
        s += partial[((size_t)nt * 16384 + p) * 2 + c];
    out[gidx] = s;
}

extern "C" void kernel_launch(void* const* d_in, const int* in_sizes, int n_in,
                              void* d_out, int out_size, void* d_ws, size_t ws_size,
                              hipStream_t stream) {
    const int*   iq     = (const int*)d_in[0];
    const int*   ir     = (const int*)d_in[1];
    const int*   ql     = (const int*)d_in[2];
    const int*   rl     = (const int*)d_in[3];
    const int*   nqi    = (const int*)d_in[4];
    const int*   nri    = (const int*)d_in[5];
    const float* emb    = (const float*)d_in[6];
    const float* gate_k = (const float*)d_in[7];
    const float* gate_b = (const float*)d_in[8];
    const float* cand_k = (const float*)d_in[9];
    const float* cand_b = (const float*)d_in[10];
    const float* w1     = (const float*)d_in[11];
    const float* b1     = (const float*)d_in[12];
    const float* w2     = (const float*)d_in[13];
    const float* b2     = (const float*)d_in[14];
    float* out = (float*)d_out;
    float* ws  = (float*)d_ws;

    float* Q       = ws;                  // 131072
    float* R       = ws + 131072;         // 131072
    float* A       = ws + 262144;         // 131072
    float* Bv      = ws + 393216;         // 131072
    float* dist    = ws + 524288;         // 16384
    float* partial = ws + 540672;         // 262144
    float* gkh     = ws + 1064960;        // 8*256*512
    float* ckh     = ws + 2113536;        // 8*256*256
    f16x8* wB      = (f16x8*)(ws + 2637824);  // ends 3162112 floats

    convert_weights<<<4096, 256, 0, stream>>>(gate_k, cand_k, gkh, ckh);
    conv_wprod<<<512, 256, 0, stream>>>(w1, wB);
    gru_encode<<<128, 1024, 0, stream>>>(iq, ir, ql, rl, emb, gkh, gate_b,
                                         ckh, cand_b, Q, R);
    dist_kernel<<<64, 256, 0, stream>>>(Q, R, dist);
    ab_kernel<<<dim3(4, 8, 2), 256, 0, stream>>>(Q, R, w1, A, Bv);
    pair_gemm<<<dim3(128, 8), 512, 0, stream>>>(Q, R, A, Bv, dist, nqi, nri,
                                                wB, w1, b1, w2, partial);
    final_reduce<<<128, 256, 0, stream>>>(partial, b2, out);
}

// Round 16
// 1416.924 us; speedup vs baseline: 2.4489x; 1.2168x over previous
//
#include <hip/hip_runtime.h>
#include <hip/hip_fp16.h>
#include <cmath>

typedef _Float16 h2 __attribute__((ext_vector_type(2)));
typedef _Float16 f16x8 __attribute__((ext_vector_type(8)));
typedef float f32x4 __attribute__((ext_vector_type(4)));

#define MFMA16 __builtin_amdgcn_mfma_f32_16x16x32_f16

#if defined(__has_builtin)
#if __has_builtin(__builtin_amdgcn_fdot2)
#define HAS_FDOT2 1
#endif
#endif

__device__ __forceinline__ float fdot2f(h2 a, h2 b, float c) {
#ifdef HAS_FDOT2
    return __builtin_amdgcn_fdot2(a, b, c, false);
#else
    c = fmaf((float)a[0], (float)b[0], c);
    return fmaf((float)a[1], (float)b[1], c);
#endif
}

__device__ __forceinline__ float sigm(float x) { return 1.0f / (1.0f + expf(-x)); }
__device__ __forceinline__ unsigned short f16b(float x) {
    _Float16 h = (_Float16)x; return __builtin_bit_cast(unsigned short, h);
}

// ---- one-shot prep: gkh/ckh (k-pair f16), wB (MFMA frags), wcomb (Wq±Wdiff) -----
// grid = 8192 x 256
__global__ __launch_bounds__(256) void conv_all(
    const float* __restrict__ gate_k, const float* __restrict__ cand_k,
    const float* __restrict__ w1,
    float* __restrict__ gkh, float* __restrict__ ckh,
    f16x8* __restrict__ wB, float* __restrict__ wcomb)
{
    int i = blockIdx.x * 256 + threadIdx.x;   // 0 .. 2097152
    if (i < 8 * 256 * 512) {                  // gkh
        int col = i & 511, kp = (i >> 9) & 255, e2 = i >> 17;
        const float* src = gate_k + ((size_t)e2 * 512 + 2 * kp) * 512 + col;
        h2 v; v[0] = (_Float16)src[0]; v[1] = (_Float16)src[512];
        gkh[i] = __builtin_bit_cast(float, v);
    }
    if (i < 8 * 256 * 256) {                  // ckh
        int col = i & 255, kp = (i >> 8) & 255, e2 = i >> 16;
        const float* src = cand_k + ((size_t)e2 * 512 + 2 * kp) * 256 + col;
        h2 v; v[0] = (_Float16)src[0]; v[1] = (_Float16)src[256];
        ckh[i] = __builtin_bit_cast(float, v);
    }
    if (i < 32 * 64 * 64) {                   // wB: [kt 32][nt 64][l 64]
        int l = i & 63, nt = (i >> 6) & 63, kt = i >> 12;
        int k0 = kt*32 + ((l >> 4) << 3);
        int n  = (nt << 4) + (l & 15);
        const float* src = w1 + (size_t)(2049 + k0) * 1024 + n;
        f16x8 v;
        #pragma unroll
        for (int j = 0; j < 8; ++j) v[j] = (_Float16)src[(size_t)j * 1024];
        wB[i] = v;
    }
    {                                         // wcomb: [mat][row*1024+n]
        int mat = i >> 20;
        int e = i & 1048575;
        const float* wmain = mat ? (w1 + (size_t)3073 * 1024) : w1;
        const float* wdiff = w1 + (size_t)1025 * 1024;
        float sgn = mat ? -1.f : 1.f;
        wcomb[i] = wmain[e] + sgn * wdiff[e];
    }
}

// ---- GRU hot loops (f16 dot2; compiler-scheduled loads — DO NOT batch/pipeline:
// round-14 showed deep load batching flips L2 into streaming-evict, FETCH 18MB->3.8GB)
__device__ __forceinline__ void gate_partial_h(
    const _Float16* in0f, float* pbuf, const float* __restrict__ gk, int tid)
{
    int cg = tid & 127, q = tid >> 7;
    int c0 = cg * 4;
    const float* gp = gk + (size_t)(q * 32) * 512 + c0;
    const _Float16* xp = in0f + q * 32 * 8;
    float4 A0 = {0.f,0.f,0.f,0.f}, A1 = {0.f,0.f,0.f,0.f};
    float4 A2 = {0.f,0.f,0.f,0.f}, A3 = {0.f,0.f,0.f,0.f};
    #pragma unroll 8
    for (int i = 0; i < 32; ++i) {
        float4 wf = *(const float4*)(gp + (size_t)i * 512);
        float4 xf = *(const float4*)(xp + i * 8);
        h2 w0 = __builtin_bit_cast(h2, wf.x), w1 = __builtin_bit_cast(h2, wf.y);
        h2 w2 = __builtin_bit_cast(h2, wf.z), w3 = __builtin_bit_cast(h2, wf.w);
        h2 x0 = __builtin_bit_cast(h2, xf.x), x1 = __builtin_bit_cast(h2, xf.y);
        h2 x2 = __builtin_bit_cast(h2, xf.z), x3 = __builtin_bit_cast(h2, xf.w);
        A0.x = fdot2f(x0, w0, A0.x); A0.y = fdot2f(x0, w1, A0.y);
        A0.z = fdot2f(x0, w2, A0.z); A0.w = fdot2f(x0, w3, A0.w);
        A1.x = fdot2f(x1, w0, A1.x); A1.y = fdot2f(x1, w1, A1.y);
        A1.z = fdot2f(x1, w2, A1.z); A1.w = fdot2f(x1, w3, A1.w);
        A2.x = fdot2f(x2, w0, A2.x); A2.y = fdot2f(x2, w1, A2.y);
        A2.z = fdot2f(x2, w2, A2.z); A2.w = fdot2f(x2, w3, A2.w);
        A3.x = fdot2f(x3, w0, A3.x); A3.y = fdot2f(x3, w1, A3.y);
        A3.z = fdot2f(x3, w2, A3.z); A3.w = fdot2f(x3, w3, A3.w);
    }
    *(float4*)&pbuf[(q * 4 + 0) * 512 + c0] = A0;
    *(float4*)&pbuf[(q * 4 + 1) * 512 + c0] = A1;
    *(float4*)&pbuf[(q * 4 + 2) * 512 + c0] = A2;
    *(float4*)&pbuf[(q * 4 + 3) * 512 + c0] = A3;
}

__device__ __forceinline__ void cand_partial_h(
    const _Float16* in0f, float* pbuf, const float* __restrict__ ck, int tid)
{
    int cg = tid & 63, q = tid >> 6;
    int c0 = cg * 4;
    const float* cp = ck + (size_t)(q * 16) * 256 + c0;
    const _Float16* xp = in0f + q * 16 * 8;
    float4 A0 = {0.f,0.f,0.f,0.f}, A1 = {0.f,0.f,0.f,0.f};
    float4 A2 = {0.f,0.f,0.f,0.f}, A3 = {0.f,0.f,0.f,0.f};
    #pragma unroll 8
    for (int i = 0; i < 16; ++i) {
        float4 wf = *(const float4*)(cp + (size_t)i * 256);
        float4 xf = *(const float4*)(xp + i * 8);
        h2 w0 = __builtin_bit_cast(h2, wf.x), w1 = __builtin_bit_cast(h2, wf.y);
        h2 w2 = __builtin_bit_cast(h2, wf.z), w3 = __builtin_bit_cast(h2, wf.w);
        h2 x0 = __builtin_bit_cast(h2, xf.x), x1 = __builtin_bit_cast(h2, xf.y);
        h2 x2 = __builtin_bit_cast(h2, xf.z), x3 = __builtin_bit_cast(h2, xf.w);
        A0.x = fdot2f(x0, w0, A0.x); A0.y = fdot2f(x0, w1, A0.y);
        A0.z = fdot2f(x0, w2, A0.z); A0.w = fdot2f(x0, w3, A0.w);
        A1.x = fdot2f(x1, w0, A1.x); A1.y = fdot2f(x1, w1, A1.y);
        A1.z = fdot2f(x1, w2, A1.z); A1.w = fdot2f(x1, w3, A1.w);
        A2.x = fdot2f(x2, w0, A2.x); A2.y = fdot2f(x2, w1, A2.y);
        A2.z = fdot2f(x2, w2, A2.z); A2.w = fdot2f(x2, w3, A2.w);
        A3.x = fdot2f(x3, w0, A3.x); A3.y = fdot2f(x3, w1, A3.y);
        A3.z = fdot2f(x3, w2, A3.z); A3.w = fdot2f(x3, w3, A3.w);
    }
    *(float4*)&pbuf[(q * 4 + 0) * 256 + c0] = A0;
    *(float4*)&pbuf[(q * 4 + 1) * 256 + c0] = A1;
    *(float4*)&pbuf[(q * 4 + 2) * 256 + c0] = A2;
    *(float4*)&pbuf[(q * 4 + 3) * 256 + c0] = A3;
}

// grid = 128 blocks x 1024 threads; block = (encoder, 4-row chunk), fully
// workgroup-local recurrence; f16 weights, fp32 h state/partials. (round-12 exact)
__global__ __launch_bounds__(1024, 4) void gru_encode(
    const int* __restrict__ iq, const int* __restrict__ ir,
    const int* __restrict__ ql, const int* __restrict__ rl,
    const float* __restrict__ emb,
    const float* __restrict__ gkh, const float* __restrict__ gate_b,
    const float* __restrict__ ckh, const float* __restrict__ cand_b,
    float* __restrict__ Qo, float* __restrict__ Ro)
{
    int bid = blockIdx.x;
    int xcd = bid & 7;
    int enc = xcd >> 1;
    int chunk = (xcd & 1) * 16 + (bid >> 3);
    int b0 = chunk * 4;
    int tid = threadIdx.x;
    int c = tid & 255, r = tid >> 8;

    const int* toks = (enc < 2) ? iq : ir;
    const int* lens = (enc < 2) ? ql : rl;
    const bool bw = (enc & 1);

    const float* gk1 = gkh + (size_t)(enc * 2 + 0) * 131072;
    const float* gk2 = gkh + (size_t)(enc * 2 + 1) * 131072;
    const float* gb1 = gate_b + (enc * 2 + 0) * 512;
    const float* gb2 = gate_b + (enc * 2 + 1) * 512;
    const float* ck1 = ckh + (size_t)(enc * 2 + 0) * 65536;
    const float* ck2 = ckh + (size_t)(enc * 2 + 1) * 65536;
    const float* cb1 = cand_b + (enc * 2 + 0) * 256;
    const float* cb2 = cand_b + (enc * 2 + 1) * 256;

    __shared__ __align__(16) _Float16 in0f[256 * 8];   // 4KB  [kp][row*2+(k&1)]
    __shared__ float pbuf[16384];                      // 64KB partials
    __shared__ float h1rt[4][256];
    __shared__ float h2rt[4][256];
    __shared__ float gzt[4][256];
    __shared__ int tok_s[4];
    __shared__ int len_s[4];

    h1rt[r][c] = 0.f;
    h2rt[r][c] = 0.f;
    if (tid < 4) len_s[tid] = lens[b0 + tid];
    __syncthreads();
    int maxlen = max(max(len_s[0], len_s[1]), max(len_s[2], len_s[3]));
    if (tid < 4) {
        int len = len_s[tid];
        tok_s[tid] = toks[(b0 + tid) * 64 + (bw ? (len - 1) : 0)];
    }
    __syncthreads();

    for (int t = 0; t < maxlen; ++t) {
        // FILL: in0f = [x_t ; h1] as f16 pairs (pair-per-thread, b32 writes)
        if (tid < 512) {
            int kp = tid >> 2, rr = tid & 3;
            float2 xv = *(const float2*)(emb + (size_t)tok_s[rr] * 256 + 2 * kp);
            h2 v; v[0] = (_Float16)xv.x; v[1] = (_Float16)xv.y;
            *(float*)(in0f + kp * 8 + rr * 2) = __builtin_bit_cast(float, v);
        } else {
            int m = (tid - 512) >> 2, rr = tid & 3;
            h2 v; v[0] = (_Float16)h1rt[rr][2 * m]; v[1] = (_Float16)h1rt[rr][2 * m + 1];
            *(float*)(in0f + (128 + m) * 8 + rr * 2) = __builtin_bit_cast(float, v);
        }
        __syncthreads();

        // ---- layer 1 ----
        gate_partial_h(in0f, pbuf, gk1, tid);
        __syncthreads();
        {
            float s0 = gb1[c], s1 = gb1[256 + c];
            #pragma unroll
            for (int q = 0; q < 8; ++q) {
                s0 += pbuf[(q * 4 + r) * 512 + c];
                s1 += pbuf[(q * 4 + r) * 512 + c + 256];
            }
            float rh = sigm(s0) * h1rt[r][c];
            gzt[r][c] = sigm(s1);
            in0f[((256 + c) >> 1) * 8 + r * 2 + (c & 1)] = (_Float16)rh;
        }
        __syncthreads();
        cand_partial_h(in0f, pbuf, ck1, tid);
        __syncthreads();
        {
            float s = cb1[c];
            #pragma unroll
            for (int q = 0; q < 16; ++q) s += pbuf[(q * 4 + r) * 256 + c];
            float cv = tanhf(s);
            float z = gzt[r][c];
            float hn = fmaf(z, h1rt[r][c] - cv, cv);
            if (t < len_s[r]) h1rt[r][c] = hn;
            in0f[(c >> 1) * 8 + r * 2 + (c & 1)]         = (_Float16)hn;
            in0f[((256 + c) >> 1) * 8 + r * 2 + (c & 1)] = (_Float16)h2rt[r][c];
        }
        __syncthreads();

        // ---- layer 2 ----
        gate_partial_h(in0f, pbuf, gk2, tid);
        __syncthreads();
        {
            float s0 = gb2[c], s1 = gb2[256 + c];
            #pragma unroll
            for (int q = 0; q < 8; ++q) {
                s0 += pbuf[(q * 4 + r) * 512 + c];
                s1 += pbuf[(q * 4 + r) * 512 + c + 256];
            }
            float rh = sigm(s0) * h2rt[r][c];
            gzt[r][c] = sigm(s1);
            in0f[((256 + c) >> 1) * 8 + r * 2 + (c & 1)] = (_Float16)rh;
        }
        __syncthreads();
        cand_partial_h(in0f, pbuf, ck2, tid);
        __syncthreads();
        {
            float s = cb2[c];
            #pragma unroll
            for (int q = 0; q < 16; ++q) s += pbuf[(q * 4 + r) * 256 + c];
            float cv = tanhf(s);
            float z = gzt[r][c];
            float hn = fmaf(z, h2rt[r][c] - cv, cv);
            if (t < len_s[r]) h2rt[r][c] = hn;
        }
        if (tid < 4) {   // token prefetch for t+1
            int t2 = t + 1;
            if (t2 < 64) {
                int len = len_s[tid];
                int tt = bw ? ((t2 < len) ? (len - 1 - t2) : t2) : t2;
                tok_s[tid] = toks[(b0 + tid) * 64 + tt];
            }
        }
        __syncthreads();
    }

    float* outp = (enc < 2) ? Qo : Ro;
    int off = (enc & 1) ? 512 : 0;
    outp[(size_t)(b0 + r) * 1024 + off + c]       = h1rt[r][c];
    outp[(size_t)(b0 + r) * 1024 + off + 256 + c] = h2rt[r][c];
}

// ---------------- ab: A = Q@(Wq+Wdiff), Bv = R@(Wr-Wdiff), combined weights ------
__global__ __launch_bounds__(256) void ab_kernel(
    const float* __restrict__ Q, const float* __restrict__ R,
    const float* __restrict__ wcomb, float* __restrict__ A, float* __restrict__ Bv)
{
    int nb = blockIdx.x, rb = blockIdx.y, mat = blockIdx.z;
    int tid = threadIdx.x;
    int n = nb * 256 + tid;
    int r0 = rb * 16;
    const float* src = mat ? R : Q;
    const float* wc  = wcomb + (size_t)mat * 1048576;

    __shared__ float Qs[16][64];
    float acc[16];
    #pragma unroll
    for (int r = 0; r < 16; ++r) acc[r] = 0.f;

    for (int k0 = 0; k0 < 1024; k0 += 64) {
        __syncthreads();
        #pragma unroll
        for (int s = 0; s < 4; ++s) {
            int e = s * 256 + tid;
            int r = e >> 6, kk = e & 63;
            Qs[r][kk] = src[(size_t)(r0 + r) * 1024 + k0 + kk];
        }
        __syncthreads();
        for (int kk = 0; kk < 64; ++kk) {
            float w = wc[(size_t)(k0 + kk) * 1024 + n];
            #pragma unroll
            for (int r = 0; r < 16; ++r)
                acc[r] = fmaf(Qs[r][kk], w, acc[r]);
        }
    }
    float* dst = mat ? Bv : A;
    #pragma unroll
    for (int r = 0; r < 16; ++r)
        dst[(size_t)(r0 + r) * 1024 + n] = acc[r];
}

// ---------------- pair GEMM: 128x128 MFMA + fused fp32 dist + fused epilogue -----
__global__ __launch_bounds__(512, 2) void pair_gemm(
    const float* __restrict__ Q, const float* __restrict__ R,
    const float* __restrict__ Aq, const float* __restrict__ Bv,
    const int* __restrict__ nqi, const int* __restrict__ nri,
    const f16x8* __restrict__ wB,
    const float* __restrict__ w1, const float* __restrict__ b1,
    const float* __restrict__ w2, float* __restrict__ partial)
{
    int bm = blockIdx.x, bn = blockIdx.y;
    int tid = threadIdx.x, w = tid >> 6, l = tid & 63;
    __shared__ __align__(16) unsigned short As[4096];    // [128 rows][32 k] f16, k-octet ^ (row&3)
    __shared__ float red[2048];                          // [8 waves][128 rows][2]
    __shared__ float dred[4][128];                       // dist partials
    __shared__ int qis[128], ris[128];
    __shared__ float dsv[128];
    if (tid < 128) {
        int p = bm*128 + tid;
        int qi = (p < 128) ? p : nqi[p-128];
        int ri = (p < 128) ? p : nri[p-128];
        qis[tid] = qi; ris[tid] = ri;
    }
    __syncthreads();

    int srow = tid & 127, skg = tid >> 7;
    const float* qrow = Q + (size_t)qis[srow]*1024 + skg*8;
    const float* rrow = R + (size_t)ris[srow]*1024 + skg*8;

    float4 qa = *(const float4*)(qrow);
    float4 qb = *(const float4*)(qrow + 4);
    float4 ra = *(const float4*)(rrow);
    float4 rb = *(const float4*)(rrow + 4);

    f32x4 acc[8];
    #pragma unroll
    for (int m = 0; m < 8; ++m) acc[m] = (f32x4){0.f,0.f,0.f,0.f};
    float dacc = 0.f;

    for (int kt = 0; kt < 32; ++kt) {
        float p0 = qa.x*ra.x, p1 = qa.y*ra.y, p2 = qa.z*ra.z, p3 = qa.w*ra.w;
        float p4 = qb.x*rb.x, p5 = qb.y*rb.y, p6 = qb.z*rb.z, p7 = qb.w*rb.w;
        dacc += ((p0 + p1) + (p2 + p3)) + ((p4 + p5) + (p6 + p7));
        f16x8 prod;
        prod[0]=(_Float16)p0; prod[1]=(_Float16)p1;
        prod[2]=(_Float16)p2; prod[3]=(_Float16)p3;
        prod[4]=(_Float16)p4; prod[5]=(_Float16)p5;
        prod[6]=(_Float16)p6; prod[7]=(_Float16)p7;
        __syncthreads();
        ((f16x8*)As)[srow*4 + (skg ^ (srow & 3))] = prod;
        __syncthreads();
        if (kt + 1 < 32) {
            qa = *(const float4*)(qrow + (kt+1)*32);
            qb = *(const float4*)(qrow + (kt+1)*32 + 4);
            ra = *(const float4*)(rrow + (kt+1)*32);
            rb = *(const float4*)(rrow + (kt+1)*32 + 4);
        }
        f16x8 bf = wB[((size_t)kt*64 + bn*8 + w)*64 + l];
        #pragma unroll
        for (int mt = 0; mt < 8; ++mt) {
            f16x8 af = ((const f16x8*)As)[(mt*16 + (l & 15))*4 + ((l >> 4) ^ (l & 3))];
            acc[mt] = MFMA16(af, bf, acc[mt], 0, 0, 0);
        }
    }

    // dist reduce: dsv[row] = sum over 4 k-quarters (fp32 exact)
    dred[skg][srow] = dacc;
    __syncthreads();
    if (tid < 128)
        dsv[tid] = (dred[0][tid] + dred[1][tid]) + (dred[2][tid] + dred[3][tid]);
    __syncthreads();

    int col = bn*128 + w*16 + (l & 15);
    float wd  = w1[(size_t)1024*1024 + col];
    float b1v = b1[col];
    float w20 = w2[col*2], w21 = w2[col*2 + 1];
    #pragma unroll
    for (int mt = 0; mt < 8; ++mt) {
        float po0[4], po1[4];
        #pragma unroll
        for (int j = 0; j < 4; ++j) {
            int lr = mt*16 + (l >> 4)*4 + j;
            float h = acc[mt][j]
                    + Aq[(size_t)qis[lr]*1024 + col]
                    + Bv[(size_t)ris[lr]*1024 + col]
                    + dsv[lr]*wd + b1v;
            h = fmaxf(h, 0.f);
            po0[j] = h * w20; po1[j] = h * w21;
        }
        #pragma unroll
        for (int s = 1; s < 16; s <<= 1) {
            #pragma unroll
            for (int j = 0; j < 4; ++j) {
                po0[j] += __shfl_xor(po0[j], s, 64);
                po1[j] += __shfl_xor(po1[j], s, 64);
            }
        }
        if ((l & 15) == 0) {
            #pragma unroll
            for (int j = 0; j < 4; ++j) {
                int row = mt*16 + (l >> 4)*4 + j;
                red[(w*128 + row)*2 + 0] = po0[j];
                red[(w*128 + row)*2 + 1] = po1[j];
            }
        }
    }
    __syncthreads();
    if (tid < 256) {
        int row = tid >> 1, cc = tid & 1;
        float s = 0.f;
        #pragma unroll
        for (int ww = 0; ww < 8; ++ww) s += red[(ww*128 + row)*2 + cc];
        partial[((size_t)bn*16384 + bm*128 + row)*2 + cc] = s;
    }
}

__global__ void final_reduce(const float* __restrict__ partial,
                             const float* __restrict__ b2, float* __restrict__ out)
{
    int gidx = blockIdx.x * 256 + threadIdx.x;
    int p = gidx >> 1, c = gidx & 1;
    float s = b2[c];
    #pragma unroll
    for (int nt = 0; nt < 8; ++nt)
        s += partial[((size_t)nt * 16384 + p) * 2 + c];
    out[gidx] = s;
}

extern "C" void kernel_launch(void* const* d_in, const int* in_sizes, int n_in,
                              void* d_out, int out_size, void* d_ws, size_t ws_size,
                              hipStream_t stream) {
    const int*   iq     = (const int*)d_in[0];
    const int*   ir     = (const int*)d_in[1];
    const int*   ql     = (const int*)d_in[2];
    const int*   rl     = (const int*)d_in[3];
    const int*   nqi    = (const int*)d_in[4];
    const int*   nri    = (const int*)d_in[5];
    const float* emb    = (const float*)d_in[6];
    const float* gate_k = (const float*)d_in[7];
    const float* gate_b = (const float*)d_in[8];
    const float* cand_k = (const float*)d_in[9];
    const float* cand_b = (const float*)d_in[10];
    const float* w1     = (const float*)d_in[11];
    const float* b1     = (const float*)d_in[12];
    const float* w2     = (const float*)d_in[13];
    const float* b2     = (const float*)d_in[14];
    float* out = (float*)d_out;
    float* ws  = (float*)d_ws;

    float* Q       = ws;                  // 131072
    float* R       = ws + 131072;         // 131072
    float* A       = ws + 262144;         // 131072
    float* Bv      = ws + 393216;         // 131072
    float* partial = ws + 540672;         // 262144
    float* gkh     = ws + 1064960;        // 8*256*512
    float* ckh     = ws + 2113536;        // 8*256*256
    f16x8* wB      = (f16x8*)(ws + 2637824);  // 131072 frags = 524288 floats
    float* wcomb   = ws + 3162112;        // 2*1024*1024 floats (ends 5259264 = 21.0 MB)

    conv_all<<<8192, 256, 0, stream>>>(gate_k, cand_k, w1, gkh, ckh, wB, wcomb);
    gru_encode<<<128, 1024, 0, stream>>>(iq, ir, ql, rl, emb, gkh, gate_b,
                                         ckh, cand_b, Q, R);
    ab_kernel<<<dim3(4, 8, 2), 256, 0, stream>>>(Q, R, wcomb, A, Bv);
    pair_gemm<<<dim3(128, 8), 512, 0, stream>>>(Q, R, A, Bv, nqi, nri,
                                                wB, w1, b1, w2, partial);
    final_reduce<<<128, 256, 0, stream>>>(partial, b2, out);
}

// Round 17
// 1334.152 us; speedup vs baseline: 2.6008x; 1.0620x over previous
//
#include <hip/hip_runtime.h>
#include <hip/hip_fp16.h>
#include <cmath>

typedef _Float16 h2 __attribute__((ext_vector_type(2)));
typedef _Float16 f16x8 __attribute__((ext_vector_type(8)));
typedef float f32x4 __attribute__((ext_vector_type(4)));

#define MFMA16 __builtin_amdgcn_mfma_f32_16x16x32_f16

#if defined(__has_builtin)
#if __has_builtin(__builtin_amdgcn_fdot2)
#define HAS_FDOT2 1
#endif
#endif

__device__ __forceinline__ float fdot2f(h2 a, h2 b, float c) {
#ifdef HAS_FDOT2
    return __builtin_amdgcn_fdot2(a, b, c, false);
#else
    c = fmaf((float)a[0], (float)b[0], c);
    return fmaf((float)a[1], (float)b[1], c);
#endif
}

__device__ __forceinline__ float sigm(float x) { return 1.0f / (1.0f + expf(-x)); }
__device__ __forceinline__ unsigned short f16b(float x) {
    _Float16 h = (_Float16)x; return __builtin_bit_cast(unsigned short, h);
}

// ---- one-shot prep: gkh/ckh (k-pair f16), wB (MFMA frags), wcomb (Wq±Wdiff) -----
__global__ __launch_bounds__(256) void conv_all(
    const float* __restrict__ gate_k, const float* __restrict__ cand_k,
    const float* __restrict__ w1,
    float* __restrict__ gkh, float* __restrict__ ckh,
    f16x8* __restrict__ wB, float* __restrict__ wcomb)
{
    int i = blockIdx.x * 256 + threadIdx.x;
    if (i < 8 * 256 * 512) {                  // gkh
        int col = i & 511, kp = (i >> 9) & 255, e2 = i >> 17;
        const float* src = gate_k + ((size_t)e2 * 512 + 2 * kp) * 512 + col;
        h2 v; v[0] = (_Float16)src[0]; v[1] = (_Float16)src[512];
        gkh[i] = __builtin_bit_cast(float, v);
    }
    if (i < 8 * 256 * 256) {                  // ckh
        int col = i & 255, kp = (i >> 8) & 255, e2 = i >> 16;
        const float* src = cand_k + ((size_t)e2 * 512 + 2 * kp) * 256 + col;
        h2 v; v[0] = (_Float16)src[0]; v[1] = (_Float16)src[256];
        ckh[i] = __builtin_bit_cast(float, v);
    }
    if (i < 32 * 64 * 64) {                   // wB: [kt 32][nt 64][l 64]
        int l = i & 63, nt = (i >> 6) & 63, kt = i >> 12;
        int k0 = kt*32 + ((l >> 4) << 3);
        int n  = (nt << 4) + (l & 15);
        const float* src = w1 + (size_t)(2049 + k0) * 1024 + n;
        f16x8 v;
        #pragma unroll
        for (int j = 0; j < 8; ++j) v[j] = (_Float16)src[(size_t)j * 1024];
        wB[i] = v;
    }
    {                                         // wcomb
        int mat = i >> 20;
        int e = i & 1048575;
        const float* wmain = mat ? (w1 + (size_t)3073 * 1024) : w1;
        const float* wdiff = w1 + (size_t)1025 * 1024;
        float sgn = mat ? -1.f : 1.f;
        wcomb[i] = wmain[e] + sgn * wdiff[e];
    }
}

// ---- GRU hot loops (f16 dot2; compiler-scheduled loads — DO NOT batch/pipeline:
// round-14 showed deep load batching flips L2 into streaming-evict, FETCH 18MB->3.8GB)
__device__ __forceinline__ void gate_partial_h(
    const _Float16* in0f, float* pbuf, const float* __restrict__ gk, int tid)
{
    int cg = tid & 127, q = tid >> 7;
    int c0 = cg * 4;
    const float* gp = gk + (size_t)(q * 32) * 512 + c0;
    const _Float16* xp = in0f + q * 32 * 8;
    float4 A0 = {0.f,0.f,0.f,0.f}, A1 = {0.f,0.f,0.f,0.f};
    float4 A2 = {0.f,0.f,0.f,0.f}, A3 = {0.f,0.f,0.f,0.f};
    #pragma unroll 8
    for (int i = 0; i < 32; ++i) {
        float4 wf = *(const float4*)(gp + (size_t)i * 512);
        float4 xf = *(const float4*)(xp + i * 8);
        h2 w0 = __builtin_bit_cast(h2, wf.x), w1 = __builtin_bit_cast(h2, wf.y);
        h2 w2 = __builtin_bit_cast(h2, wf.z), w3 = __builtin_bit_cast(h2, wf.w);
        h2 x0 = __builtin_bit_cast(h2, xf.x), x1 = __builtin_bit_cast(h2, xf.y);
        h2 x2 = __builtin_bit_cast(h2, xf.z), x3 = __builtin_bit_cast(h2, xf.w);
        A0.x = fdot2f(x0, w0, A0.x); A0.y = fdot2f(x0, w1, A0.y);
        A0.z = fdot2f(x0, w2, A0.z); A0.w = fdot2f(x0, w3, A0.w);
        A1.x = fdot2f(x1, w0, A1.x); A1.y = fdot2f(x1, w1, A1.y);
        A1.z = fdot2f(x1, w2, A1.z); A1.w = fdot2f(x1, w3, A1.w);
        A2.x = fdot2f(x2, w0, A2.x); A2.y = fdot2f(x2, w1, A2.y);
        A2.z = fdot2f(x2, w2, A2.z); A2.w = fdot2f(x2, w3, A2.w);
        A3.x = fdot2f(x3, w0, A3.x); A3.y = fdot2f(x3, w1, A3.y);
        A3.z = fdot2f(x3, w2, A3.z); A3.w = fdot2f(x3, w3, A3.w);
    }
    *(float4*)&pbuf[(q * 4 + 0) * 512 + c0] = A0;
    *(float4*)&pbuf[(q * 4 + 1) * 512 + c0] = A1;
    *(float4*)&pbuf[(q * 4 + 2) * 512 + c0] = A2;
    *(float4*)&pbuf[(q * 4 + 3) * 512 + c0] = A3;
}

__device__ __forceinline__ void cand_partial_h(
    const _Float16* in0f, float* pbuf, const float* __restrict__ ck, int tid)
{
    int cg = tid & 63, q = tid >> 6;
    int c0 = cg * 4;
    const float* cp = ck + (size_t)(q * 16) * 256 + c0;
    const _Float16* xp = in0f + q * 16 * 8;
    float4 A0 = {0.f,0.f,0.f,0.f}, A1 = {0.f,0.f,0.f,0.f};
    float4 A2 = {0.f,0.f,0.f,0.f}, A3 = {0.f,0.f,0.f,0.f};
    #pragma unroll 8
    for (int i = 0; i < 16; ++i) {
        float4 wf = *(const float4*)(cp + (size_t)i * 256);
        float4 xf = *(const float4*)(xp + i * 8);
        h2 w0 = __builtin_bit_cast(h2, wf.x), w1 = __builtin_bit_cast(h2, wf.y);
        h2 w2 = __builtin_bit_cast(h2, wf.z), w3 = __builtin_bit_cast(h2, wf.w);
        h2 x0 = __builtin_bit_cast(h2, xf.x), x1 = __builtin_bit_cast(h2, xf.y);
        h2 x2 = __builtin_bit_cast(h2, xf.z), x3 = __builtin_bit_cast(h2, xf.w);
        A0.x = fdot2f(x0, w0, A0.x); A0.y = fdot2f(x0, w1, A0.y);
        A0.z = fdot2f(x0, w2, A0.z); A0.w = fdot2f(x0, w3, A0.w);
        A1.x = fdot2f(x1, w0, A1.x); A1.y = fdot2f(x1, w1, A1.y);
        A1.z = fdot2f(x1, w2, A1.z); A1.w = fdot2f(x1, w3, A1.w);
        A2.x = fdot2f(x2, w0, A2.x); A2.y = fdot2f(x2, w1, A2.y);
        A2.z = fdot2f(x2, w2, A2.z); A2.w = fdot2f(x2, w3, A2.w);
        A3.x = fdot2f(x3, w0, A3.x); A3.y = fdot2f(x3, w1, A3.y);
        A3.z = fdot2f(x3, w2, A3.z); A3.w = fdot2f(x3, w3, A3.w);
    }
    *(float4*)&pbuf[(q * 4 + 0) * 256 + c0] = A0;
    *(float4*)&pbuf[(q * 4 + 1) * 256 + c0] = A1;
    *(float4*)&pbuf[(q * 4 + 2) * 256 + c0] = A2;
    *(float4*)&pbuf[(q * 4 + 3) * 256 + c0] = A3;
}

// grid = 128 blocks x 1024 threads; block = (encoder, 4-row chunk); split A/B input
// buffers let the FILL phase fold into the cand epilogues (8 barriers/step, was 9).
__global__ __launch_bounds__(1024, 4) void gru_encode(
    const int* __restrict__ iq, const int* __restrict__ ir,
    const int* __restrict__ ql, const int* __restrict__ rl,
    const float* __restrict__ emb,
    const float* __restrict__ gkh, const float* __restrict__ gate_b,
    const float* __restrict__ ckh, const float* __restrict__ cand_b,
    float* __restrict__ Qo, float* __restrict__ Ro)
{
    int bid = blockIdx.x;
    int xcd = bid & 7;
    int enc = xcd >> 1;
    int chunk = (xcd & 1) * 16 + (bid >> 3);
    int b0 = chunk * 4;
    int tid = threadIdx.x;
    int c = tid & 255, r = tid >> 8;

    const int* toks = (enc < 2) ? iq : ir;
    const int* lens = (enc < 2) ? ql : rl;
    const bool bw = (enc & 1);

    const float* gk1 = gkh + (size_t)(enc * 2 + 0) * 131072;
    const float* gk2 = gkh + (size_t)(enc * 2 + 1) * 131072;
    const float* gb1 = gate_b + (enc * 2 + 0) * 512;
    const float* gb2 = gate_b + (enc * 2 + 1) * 512;
    const float* ck1 = ckh + (size_t)(enc * 2 + 0) * 65536;
    const float* ck2 = ckh + (size_t)(enc * 2 + 1) * 65536;
    const float* cb1 = cand_b + (enc * 2 + 0) * 256;
    const float* cb2 = cand_b + (enc * 2 + 1) * 256;

    __shared__ __align__(16) _Float16 in0fA[256 * 8];  // layer-1 input [x ; h1]
    __shared__ __align__(16) _Float16 in0fB[256 * 8];  // layer-2 input [h1n ; h2]
    __shared__ float pbuf[16384];
    __shared__ float h1rt[4][256];
    __shared__ float h2rt[4][256];
    __shared__ float gzt[4][256];
    __shared__ int len_s[4];

    h1rt[r][c] = 0.f;
    h2rt[r][c] = 0.f;
    if (tid < 4) len_s[tid] = lens[b0 + tid];
    __syncthreads();
    int maxlen = max(max(len_s[0], len_s[1]), max(len_s[2], len_s[3]));
    // init in0fA: x(0) | h1(0)=0
    if (tid < 512) {
        int kp = tid >> 2, rr = tid & 3;
        int len = len_s[rr];
        int tok = toks[(b0 + rr) * 64 + (bw ? (len - 1) : 0)];
        float2 xv = *(const float2*)(emb + (size_t)tok * 256 + 2 * kp);
        h2 v; v[0] = (_Float16)xv.x; v[1] = (_Float16)xv.y;
        *(float*)(in0fA + kp * 8 + rr * 2) = __builtin_bit_cast(float, v);
    } else {
        int m = (tid - 512) >> 2, rr = tid & 3;
        *(unsigned int*)(in0fA + (128 + m) * 8 + rr * 2) = 0u;
    }
    __syncthreads();

    for (int t = 0; t < maxlen; ++t) {
        // ---- layer 1 ----
        gate_partial_h(in0fA, pbuf, gk1, tid);
        __syncthreads();
        {   // red1: r-gate -> in0fA h-half = f16(rv*h1); z -> gzt
            float s0 = gb1[c], s1 = gb1[256 + c];
            #pragma unroll
            for (int q = 0; q < 8; ++q) {
                s0 += pbuf[(q * 4 + r) * 512 + c];
                s1 += pbuf[(q * 4 + r) * 512 + c + 256];
            }
            float rh = sigm(s0) * h1rt[r][c];
            gzt[r][c] = sigm(s1);
            in0fA[((256 + c) >> 1) * 8 + r * 2 + (c & 1)] = (_Float16)rh;
        }
        __syncthreads();
        cand_partial_h(in0fA, pbuf, ck1, tid);
        __syncthreads();
        {   // red1b: h1 update; stage layer-2 input; stage next-step h1 into in0fA
            float s = cb1[c];
            #pragma unroll
            for (int q = 0; q < 16; ++q) s += pbuf[(q * 4 + r) * 256 + c];
            float cv = tanhf(s);
            float z = gzt[r][c];
            float hn = fmaf(z, h1rt[r][c] - cv, cv);
            float hm = (t < len_s[r]) ? hn : h1rt[r][c];
            h1rt[r][c] = hm;
            in0fB[(c >> 1) * 8 + r * 2 + (c & 1)]         = (_Float16)hn;          // layer-2 x (unmasked)
            in0fB[((256 + c) >> 1) * 8 + r * 2 + (c & 1)] = (_Float16)h2rt[r][c];  // layer-2 h
            in0fA[((256 + c) >> 1) * 8 + r * 2 + (c & 1)] = (_Float16)hm;          // next-step h1
        }
        __syncthreads();

        // ---- layer 2 ----
        gate_partial_h(in0fB, pbuf, gk2, tid);
        __syncthreads();
        {
            float s0 = gb2[c], s1 = gb2[256 + c];
            #pragma unroll
            for (int q = 0; q < 8; ++q) {
                s0 += pbuf[(q * 4 + r) * 512 + c];
                s1 += pbuf[(q * 4 + r) * 512 + c + 256];
            }
            float rh = sigm(s0) * h2rt[r][c];
            gzt[r][c] = sigm(s1);
            in0fB[((256 + c) >> 1) * 8 + r * 2 + (c & 1)] = (_Float16)rh;
        }
        __syncthreads();
        cand_partial_h(in0fB, pbuf, ck2, tid);
        __syncthreads();
        {   // red2b: h2 update; gather x(t+1) into in0fA (per-thread token calc)
            float s = cb2[c];
            #pragma unroll
            for (int q = 0; q < 16; ++q) s += pbuf[(q * 4 + r) * 256 + c];
            float cv = tanhf(s);
            float z = gzt[r][c];
            float hn = fmaf(z, h2rt[r][c] - cv, cv);
            if (t < len_s[r]) h2rt[r][c] = hn;
        }
        if (tid < 512) {
            int t2 = t + 1;
            if (t2 < 64) {
                int kp = tid >> 2, rr = tid & 3;
                int len = len_s[rr];
                int tt = bw ? ((t2 < len) ? (len - 1 - t2) : t2) : t2;
                int tok = toks[(b0 + rr) * 64 + tt];
                float2 xv = *(const float2*)(emb + (size_t)tok * 256 + 2 * kp);
                h2 v; v[0] = (_Float16)xv.x; v[1] = (_Float16)xv.y;
                *(float*)(in0fA + kp * 8 + rr * 2) = __builtin_bit_cast(float, v);
            }
        }
        __syncthreads();
    }

    float* outp = (enc < 2) ? Qo : Ro;
    int off = (enc & 1) ? 512 : 0;
    outp[(size_t)(b0 + r) * 1024 + off + c]       = h1rt[r][c];
    outp[(size_t)(b0 + r) * 1024 + off + 256 + c] = h2rt[r][c];
}

// ---------------- ab: A = Q@(Wq+Wdiff), Bv = R@(Wr-Wdiff); 256 blocks ------------
__global__ __launch_bounds__(256) void ab_kernel(
    const float* __restrict__ Q, const float* __restrict__ R,
    const float* __restrict__ wcomb, float* __restrict__ A, float* __restrict__ Bv)
{
    int nb = blockIdx.x, rb = blockIdx.y, mat = blockIdx.z;
    int tid = threadIdx.x;
    int n = nb * 256 + tid;
    int r0 = rb * 4;
    const float* src = mat ? R : Q;
    const float* wc  = wcomb + (size_t)mat * 1048576;

    __shared__ float Qs[4][64];
    float acc[4] = {0.f, 0.f, 0.f, 0.f};

    for (int k0 = 0; k0 < 1024; k0 += 64) {
        __syncthreads();
        {
            int rr = tid >> 6, kk = tid & 63;
            Qs[rr][kk] = src[(size_t)(r0 + rr) * 1024 + k0 + kk];
        }
        __syncthreads();
        for (int kk = 0; kk < 64; ++kk) {
            float w = wc[(size_t)(k0 + kk) * 1024 + n];
            #pragma unroll
            for (int r = 0; r < 4; ++r)
                acc[r] = fmaf(Qs[r][kk], w, acc[r]);
        }
    }
    float* dst = mat ? Bv : A;
    #pragma unroll
    for (int r = 0; r < 4; ++r)
        dst[(size_t)(r0 + r) * 1024 + n] = acc[r];
}

// ---------------- pair GEMM: 128x128 MFMA + fused fp32 dist + fused epilogue -----
__global__ __launch_bounds__(512, 2) void pair_gemm(
    const float* __restrict__ Q, const float* __restrict__ R,
    const float* __restrict__ Aq, const float* __restrict__ Bv,
    const int* __restrict__ nqi, const int* __restrict__ nri,
    const f16x8* __restrict__ wB,
    const float* __restrict__ w1, const float* __restrict__ b1,
    const float* __restrict__ w2, float* __restrict__ partial)
{
    int bm = blockIdx.x, bn = blockIdx.y;
    int tid = threadIdx.x, w = tid >> 6, l = tid & 63;
    __shared__ __align__(16) unsigned short As[4096];
    __shared__ float red[2048];
    __shared__ float dred[4][128];
    __shared__ int qis[128], ris[128];
    __shared__ float dsv[128];
    if (tid < 128) {
        int p = bm*128 + tid;
        int qi = (p < 128) ? p : nqi[p-128];
        int ri = (p < 128) ? p : nri[p-128];
        qis[tid] = qi; ris[tid] = ri;
    }
    __syncthreads();

    int srow = tid & 127, skg = tid >> 7;
    const float* qrow = Q + (size_t)qis[srow]*1024 + skg*8;
    const float* rrow = R + (size_t)ris[srow]*1024 + skg*8;

    float4 qa = *(const float4*)(qrow);
    float4 qb = *(const float4*)(qrow + 4);
    float4 ra = *(const float4*)(rrow);
    float4 rb = *(const float4*)(rrow + 4);

    f32x4 acc[8];
    #pragma unroll
    for (int m = 0; m < 8; ++m) acc[m] = (f32x4){0.f,0.f,0.f,0.f};
    float dacc = 0.f;

    for (int kt = 0; kt < 32; ++kt) {
        float p0 = qa.x*ra.x, p1 = qa.y*ra.y, p2 = qa.z*ra.z, p3 = qa.w*ra.w;
        float p4 = qb.x*rb.x, p5 = qb.y*rb.y, p6 = qb.z*rb.z, p7 = qb.w*rb.w;
        dacc += ((p0 + p1) + (p2 + p3)) + ((p4 + p5) + (p6 + p7));
        f16x8 prod;
        prod[0]=(_Float16)p0; prod[1]=(_Float16)p1;
        prod[2]=(_Float16)p2; prod[3]=(_Float16)p3;
        prod[4]=(_Float16)p4; prod[5]=(_Float16)p5;
        prod[6]=(_Float16)p6; prod[7]=(_Float16)p7;
        __syncthreads();
        ((f16x8*)As)[srow*4 + (skg ^ (srow & 3))] = prod;
        __syncthreads();
        if (kt + 1 < 32) {
            qa = *(const float4*)(qrow + (kt+1)*32);
            qb = *(const float4*)(qrow + (kt+1)*32 + 4);
            ra = *(const float4*)(rrow + (kt+1)*32);
            rb = *(const float4*)(rrow + (kt+1)*32 + 4);
        }
        f16x8 bf = wB[((size_t)kt*64 + bn*8 + w)*64 + l];
        #pragma unroll
        for (int mt = 0; mt < 8; ++mt) {
            f16x8 af = ((const f16x8*)As)[(mt*16 + (l & 15))*4 + ((l >> 4) ^ (l & 3))];
            acc[mt] = MFMA16(af, bf, acc[mt], 0, 0, 0);
        }
    }

    dred[skg][srow] = dacc;
    __syncthreads();
    if (tid < 128)
        dsv[tid] = (dred[0][tid] + dred[1][tid]) + (dred[2][tid] + dred[3][tid]);
    __syncthreads();

    int col = bn*128 + w*16 + (l & 15);
    float wd  = w1[(size_t)1024*1024 + col];
    float b1v = b1[col];
    float w20 = w2[col*2], w21 = w2[col*2 + 1];
    #pragma unroll
    for (int mt = 0; mt < 8; ++mt) {
        float po0[4], po1[4];
        #pragma unroll
        for (int j = 0; j < 4; ++j) {
            int lr = mt*16 + (l >> 4)*4 + j;
            float h = acc[mt][j]
                    + Aq[(size_t)qis[lr]*1024 + col]
                    + Bv[(size_t)ris[lr]*1024 + col]
                    + dsv[lr]*wd + b1v;
            h = fmaxf(h, 0.f);
            po0[j] = h * w20; po1[j] = h * w21;
        }
        #pragma unroll
        for (int s = 1; s < 16; s <<= 1) {
            #pragma unroll
            for (int j = 0; j < 4; ++j) {
                po0[j] += __shfl_xor(po0[j], s, 64);
                po1[j] += __shfl_xor(po1[j], s, 64);
            }
        }
        if ((l & 15) == 0) {
            #pragma unroll
            for (int j = 0; j < 4; ++j) {
                int row = mt*16 + (l >> 4)*4 + j;
                red[(w*128 + row)*2 + 0] = po0[j];
                red[(w*128 + row)*2 + 1] = po1[j];
            }
        }
    }
    __syncthreads();
    if (tid < 256) {
        int row = tid >> 1, cc = tid & 1;
        float s = 0.f;
        #pragma unroll
        for (int ww = 0; ww < 8; ++ww) s += red[(ww*128 + row)*2 + cc];
        partial[((size_t)bn*16384 + bm*128 + row)*2 + cc] = s;
    }
}

__global__ void final_reduce(const float* __restrict__ partial,
                             const float* __restrict__ b2, float* __restrict__ out)
{
    int gidx = blockIdx.x * 256 + threadIdx.x;
    int p = gidx >> 1, c = gidx & 1;
    float s = b2[c];
    #pragma unroll
    for (int nt = 0; nt < 8; ++nt)
        s += partial[((size_t)nt * 16384 + p) * 2 + c];
    out[gidx] = s;
}

extern "C" void kernel_launch(void* const* d_in, const int* in_sizes, int n_in,
                              void* d_out, int out_size, void* d_ws, size_t ws_size,
                              hipStream_t stream) {
    const int*   iq     = (const int*)d_in[0];
    const int*   ir     = (const int*)d_in[1];
    const int*   ql     = (const int*)d_in[2];
    const int*   rl     = (const int*)d_in[3];
    const int*   nqi    = (const int*)d_in[4];
    const int*   nri    = (const int*)d_in[5];
    const float* emb    = (const float*)d_in[6];
    const float* gate_k = (const float*)d_in[7];
    const float* gate_b = (const float*)d_in[8];
    const float* cand_k = (const float*)d_in[9];
    const float* cand_b = (const float*)d_in[10];
    const float* w1     = (const float*)d_in[11];
    const float* b1     = (const float*)d_in[12];
    const float* w2     = (const float*)d_in[13];
    const float* b2     = (const float*)d_in[14];
    float* out = (float*)d_out;
    float* ws  = (float*)d_ws;

    float* Q       = ws;                  // 131072
    float* R       = ws + 131072;         // 131072
    float* A       = ws + 262144;         // 131072
    float* Bv      = ws + 393216;         // 131072
    float* partial = ws + 540672;         // 262144
    float* gkh     = ws + 1064960;        // 8*256*512
    float* ckh     = ws + 2113536;        // 8*256*256
    f16x8* wB      = (f16x8*)(ws + 2637824);  // 131072 frags = 524288 floats
    float* wcomb   = ws + 3162112;        // 2*1024*1024 (ends 5259264 = 21.0 MB)

    conv_all<<<8192, 256, 0, stream>>>(gate_k, cand_k, w1, gkh, ckh, wB, wcomb);
    gru_encode<<<128, 1024, 0, stream>>>(iq, ir, ql, rl, emb, gkh, gate_b,
                                         ckh, cand_b, Q, R);
    ab_kernel<<<dim3(4, 32, 2), 256, 0, stream>>>(Q, R, wcomb, A, Bv);
    pair_gemm<<<dim3(128, 8), 512, 0, stream>>>(Q, R, A, Bv, nqi, nri,
                                                wB, w1, b1, w2, partial);
    final_reduce<<<128, 256, 0, stream>>>(partial, b2, out);
}

// Round 18
// 1084.050 us; speedup vs baseline: 3.2009x; 1.2307x over previous
//
#include <hip/hip_runtime.h>
#include <hip/hip_fp16.h>
#include <cmath>

typedef _Float16 h2 __attribute__((ext_vector_type(2)));
typedef _Float16 f16x8 __attribute__((ext_vector_type(8)));
typedef float f32x4 __attribute__((ext_vector_type(4)));

#define MFMA16 __builtin_amdgcn_mfma_f32_16x16x32_f16

#if defined(__has_builtin)
#if __has_builtin(__builtin_amdgcn_fdot2)
#define HAS_FDOT2 1
#endif
#endif

__device__ __forceinline__ float fdot2f(h2 a, h2 b, float c) {
#ifdef HAS_FDOT2
    return __builtin_amdgcn_fdot2(a, b, c, false);
#else
    c = fmaf((float)a[0], (float)b[0], c);
    return fmaf((float)a[1], (float)b[1], c);
#endif
}

__device__ __forceinline__ float sigm(float x) { return 1.0f / (1.0f + expf(-x)); }
__device__ __forceinline__ unsigned short f16b(float x) {
    _Float16 h = (_Float16)x; return __builtin_bit_cast(unsigned short, h);
}

// ---- one-shot prep: gkh/ckh (k-pair f16), wB (MFMA frags), wcomb (Wq±Wdiff) -----
__global__ __launch_bounds__(256) void conv_all(
    const float* __restrict__ gate_k, const float* __restrict__ cand_k,
    const float* __restrict__ w1,
    float* __restrict__ gkh, float* __restrict__ ckh,
    f16x8* __restrict__ wB, float* __restrict__ wcomb)
{
    int i = blockIdx.x * 256 + threadIdx.x;
    if (i < 8 * 256 * 512) {                  // gkh
        int col = i & 511, kp = (i >> 9) & 255, e2 = i >> 17;
        const float* src = gate_k + ((size_t)e2 * 512 + 2 * kp) * 512 + col;
        h2 v; v[0] = (_Float16)src[0]; v[1] = (_Float16)src[512];
        gkh[i] = __builtin_bit_cast(float, v);
    }
    if (i < 8 * 256 * 256) {                  // ckh
        int col = i & 255, kp = (i >> 8) & 255, e2 = i >> 16;
        const float* src = cand_k + ((size_t)e2 * 512 + 2 * kp) * 256 + col;
        h2 v; v[0] = (_Float16)src[0]; v[1] = (_Float16)src[256];
        ckh[i] = __builtin_bit_cast(float, v);
    }
    if (i < 32 * 64 * 64) {                   // wB: [kt 32][nt 64][l 64]
        int l = i & 63, nt = (i >> 6) & 63, kt = i >> 12;
        int k0 = kt*32 + ((l >> 4) << 3);
        int n  = (nt << 4) + (l & 15);
        const float* src = w1 + (size_t)(2049 + k0) * 1024 + n;
        f16x8 v;
        #pragma unroll
        for (int j = 0; j < 8; ++j) v[j] = (_Float16)src[(size_t)j * 1024];
        wB[i] = v;
    }
    {                                         // wcomb
        int mat = i >> 20;
        int e = i & 1048575;
        const float* wmain = mat ? (w1 + (size_t)3073 * 1024) : w1;
        const float* wdiff = w1 + (size_t)1025 * 1024;
        float sgn = mat ? -1.f : 1.f;
        wcomb[i] = wmain[e] + sgn * wdiff[e];
    }
}

// ---- GRU hot loops, BR=2 (f16 dot2; compiler-scheduled loads — DO NOT batch:
// round-14 showed deep load batching flips L2 into streaming-evict).
// in0f layout (2 rows): f16 element (k, row) at (k>>1)*4 + row*2 + (k&1)
__device__ __forceinline__ void gate_partial_h(
    const _Float16* in0f, float* pbuf, const float* __restrict__ gk, int tid)
{
    int cg = tid & 127, q = tid >> 7;
    int c0 = cg * 4;
    const float* gp = gk + (size_t)(q * 32) * 512 + c0;
    const _Float16* xp = in0f + q * 32 * 4;
    float4 A0 = {0.f,0.f,0.f,0.f}, A1 = {0.f,0.f,0.f,0.f};
    #pragma unroll 8
    for (int i = 0; i < 32; ++i) {
        float4 wf = *(const float4*)(gp + (size_t)i * 512);
        float2 xf = *(const float2*)(xp + i * 4);
        h2 w0 = __builtin_bit_cast(h2, wf.x), w1 = __builtin_bit_cast(h2, wf.y);
        h2 w2 = __builtin_bit_cast(h2, wf.z), w3 = __builtin_bit_cast(h2, wf.w);
        h2 x0 = __builtin_bit_cast(h2, xf.x), x1 = __builtin_bit_cast(h2, xf.y);
        A0.x = fdot2f(x0, w0, A0.x); A0.y = fdot2f(x0, w1, A0.y);
        A0.z = fdot2f(x0, w2, A0.z); A0.w = fdot2f(x0, w3, A0.w);
        A1.x = fdot2f(x1, w0, A1.x); A1.y = fdot2f(x1, w1, A1.y);
        A1.z = fdot2f(x1, w2, A1.z); A1.w = fdot2f(x1, w3, A1.w);
    }
    *(float4*)&pbuf[(q * 2 + 0) * 512 + c0] = A0;
    *(float4*)&pbuf[(q * 2 + 1) * 512 + c0] = A1;
}

__device__ __forceinline__ void cand_partial_h(
    const _Float16* in0f, float* pbuf, const float* __restrict__ ck, int tid)
{
    int cg = tid & 63, q = tid >> 6;
    int c0 = cg * 4;
    const float* cp = ck + (size_t)(q * 16) * 256 + c0;
    const _Float16* xp = in0f + q * 16 * 4;
    float4 A0 = {0.f,0.f,0.f,0.f}, A1 = {0.f,0.f,0.f,0.f};
    #pragma unroll 8
    for (int i = 0; i < 16; ++i) {
        float4 wf = *(const float4*)(cp + (size_t)i * 256);
        float2 xf = *(const float2*)(xp + i * 4);
        h2 w0 = __builtin_bit_cast(h2, wf.x), w1 = __builtin_bit_cast(h2, wf.y);
        h2 w2 = __builtin_bit_cast(h2, wf.z), w3 = __builtin_bit_cast(h2, wf.w);
        h2 x0 = __builtin_bit_cast(h2, xf.x), x1 = __builtin_bit_cast(h2, xf.y);
        A0.x = fdot2f(x0, w0, A0.x); A0.y = fdot2f(x0, w1, A0.y);
        A0.z = fdot2f(x0, w2, A0.z); A0.w = fdot2f(x0, w3, A0.w);
        A1.x = fdot2f(x1, w0, A1.x); A1.y = fdot2f(x1, w1, A1.y);
        A1.z = fdot2f(x1, w2, A1.z); A1.w = fdot2f(x1, w3, A1.w);
    }
    *(float4*)&pbuf[(q * 2 + 0) * 256 + c0] = A0;
    *(float4*)&pbuf[(q * 2 + 1) * 256 + c0] = A1;
}

// grid = 256 blocks x 1024 threads; block = (encoder, 2-row chunk): all 256 CUs
// active, per-thread issue halved, per-block load pattern identical to round-12.
__global__ __launch_bounds__(1024, 4) void gru_encode(
    const int* __restrict__ iq, const int* __restrict__ ir,
    const int* __restrict__ ql, const int* __restrict__ rl,
    const float* __restrict__ emb,
    const float* __restrict__ gkh, const float* __restrict__ gate_b,
    const float* __restrict__ ckh, const float* __restrict__ cand_b,
    float* __restrict__ Qo, float* __restrict__ Ro)
{
    int bid = blockIdx.x;
    int xcd = bid & 7;
    int enc = xcd >> 1;
    int chunk = (xcd & 1) * 32 + (bid >> 3);   // 0..63
    int b0 = chunk * 2;
    int tid = threadIdx.x;

    const int* toks = (enc < 2) ? iq : ir;
    const int* lens = (enc < 2) ? ql : rl;
    const bool bw = (enc & 1);

    const float* gk1 = gkh + (size_t)(enc * 2 + 0) * 131072;
    const float* gk2 = gkh + (size_t)(enc * 2 + 1) * 131072;
    const float* gb1 = gate_b + (enc * 2 + 0) * 512;
    const float* gb2 = gate_b + (enc * 2 + 1) * 512;
    const float* ck1 = ckh + (size_t)(enc * 2 + 0) * 65536;
    const float* ck2 = ckh + (size_t)(enc * 2 + 1) * 65536;
    const float* cb1 = cand_b + (enc * 2 + 0) * 256;
    const float* cb2 = cand_b + (enc * 2 + 1) * 256;

    __shared__ __align__(16) _Float16 in0fA[256 * 4];  // 2KB layer-1 input [x ; h1]
    __shared__ __align__(16) _Float16 in0fB[256 * 4];  // 2KB layer-2 input [h1n ; h2]
    __shared__ float pbuf[8192];                       // 32KB partials
    __shared__ float h1rt[2][256];
    __shared__ float h2rt[2][256];
    __shared__ float gzt[2][256];
    __shared__ int len_s[2];

    if (tid < 512) { int r = tid >> 8, c = tid & 255; h1rt[r][c] = 0.f; h2rt[r][c] = 0.f; }
    if (tid < 2) len_s[tid] = lens[b0 + tid];
    __syncthreads();
    int maxlen = max(len_s[0], len_s[1]);
    if (tid < 256) {           // init x(0)
        int kp = tid >> 1, rr = tid & 1;
        int len = len_s[rr];
        int tok = toks[(b0 + rr) * 64 + (bw ? (len - 1) : 0)];
        float2 xv = *(const float2*)(emb + (size_t)tok * 256 + 2 * kp);
        h2 v; v[0] = (_Float16)xv.x; v[1] = (_Float16)xv.y;
        *(float*)(in0fA + kp * 4 + rr * 2) = __builtin_bit_cast(float, v);
    } else if (tid < 512) {    // h1(0) = 0
        int m = (tid - 256) >> 1, rr = tid & 1;
        *(unsigned int*)(in0fA + (128 + m) * 4 + rr * 2) = 0u;
    }
    __syncthreads();

    for (int t = 0; t < maxlen; ++t) {
        // ---- layer 1 ----
        gate_partial_h(in0fA, pbuf, gk1, tid);
        __syncthreads();
        if (tid < 512) {
            int c = tid & 255, r = tid >> 8;
            float s0 = gb1[c], s1 = gb1[256 + c];
            #pragma unroll
            for (int q = 0; q < 8; ++q) {
                s0 += pbuf[(q * 2 + r) * 512 + c];
                s1 += pbuf[(q * 2 + r) * 512 + c + 256];
            }
            float rh = sigm(s0) * h1rt[r][c];
            gzt[r][c] = sigm(s1);
            in0fA[((256 + c) >> 1) * 4 + r * 2 + (c & 1)] = (_Float16)rh;
        }
        __syncthreads();
        cand_partial_h(in0fA, pbuf, ck1, tid);
        __syncthreads();
        if (tid < 512) {
            int c = tid & 255, r = tid >> 8;
            float s = cb1[c];
            #pragma unroll
            for (int q = 0; q < 16; ++q) s += pbuf[(q * 2 + r) * 256 + c];
            float cv = tanhf(s);
            float z = gzt[r][c];
            float hn = fmaf(z, h1rt[r][c] - cv, cv);
            float hm = (t < len_s[r]) ? hn : h1rt[r][c];
            h1rt[r][c] = hm;
            in0fB[(c >> 1) * 4 + r * 2 + (c & 1)]         = (_Float16)hn;          // layer-2 x (unmasked)
            in0fB[((256 + c) >> 1) * 4 + r * 2 + (c & 1)] = (_Float16)h2rt[r][c];  // layer-2 h
            in0fA[((256 + c) >> 1) * 4 + r * 2 + (c & 1)] = (_Float16)hm;          // next-step h1
        }
        __syncthreads();

        // ---- layer 2 ----
        gate_partial_h(in0fB, pbuf, gk2, tid);
        __syncthreads();
        if (tid < 512) {
            int c = tid & 255, r = tid >> 8;
            float s0 = gb2[c], s1 = gb2[256 + c];
            #pragma unroll
            for (int q = 0; q < 8; ++q) {
                s0 += pbuf[(q * 2 + r) * 512 + c];
                s1 += pbuf[(q * 2 + r) * 512 + c + 256];
            }
            float rh = sigm(s0) * h2rt[r][c];
            gzt[r][c] = sigm(s1);
            in0fB[((256 + c) >> 1) * 4 + r * 2 + (c & 1)] = (_Float16)rh;
        }
        __syncthreads();
        cand_partial_h(in0fB, pbuf, ck2, tid);
        __syncthreads();
        if (tid < 512) {
            int c = tid & 255, r = tid >> 8;
            float s = cb2[c];
            #pragma unroll
            for (int q = 0; q < 16; ++q) s += pbuf[(q * 2 + r) * 256 + c];
            float cv = tanhf(s);
            float z = gzt[r][c];
            float hn = fmaf(z, h2rt[r][c] - cv, cv);
            if (t < len_s[r]) h2rt[r][c] = hn;
        }
        if (tid < 256) {   // gather x(t+1)
            int t2 = t + 1;
            if (t2 < 64) {
                int kp = tid >> 1, rr = tid & 1;
                int len = len_s[rr];
                int tt = bw ? ((t2 < len) ? (len - 1 - t2) : t2) : t2;
                int tok = toks[(b0 + rr) * 64 + tt];
                float2 xv = *(const float2*)(emb + (size_t)tok * 256 + 2 * kp);
                h2 v; v[0] = (_Float16)xv.x; v[1] = (_Float16)xv.y;
                *(float*)(in0fA + kp * 4 + rr * 2) = __builtin_bit_cast(float, v);
            }
        }
        __syncthreads();
    }

    if (tid < 512) {
        int r = tid >> 8, c = tid & 255;
        float* outp = (enc < 2) ? Qo : Ro;
        int off = (enc & 1) ? 512 : 0;
        outp[(size_t)(b0 + r) * 1024 + off + c]       = h1rt[r][c];
        outp[(size_t)(b0 + r) * 1024 + off + 256 + c] = h2rt[r][c];
    }
}

// ---------------- ab: A = Q@(Wq+Wdiff), Bv = R@(Wr-Wdiff); 256 blocks ------------
__global__ __launch_bounds__(256) void ab_kernel(
    const float* __restrict__ Q, const float* __restrict__ R,
    const float* __restrict__ wcomb, float* __restrict__ A, float* __restrict__ Bv)
{
    int nb = blockIdx.x, rb = blockIdx.y, mat = blockIdx.z;
    int tid = threadIdx.x;
    int n = nb * 256 + tid;
    int r0 = rb * 4;
    const float* src = mat ? R : Q;
    const float* wc  = wcomb + (size_t)mat * 1048576;

    __shared__ float Qs[4][64];
    float acc[4] = {0.f, 0.f, 0.f, 0.f};

    for (int k0 = 0; k0 < 1024; k0 += 64) {
        __syncthreads();
        {
            int rr = tid >> 6, kk = tid & 63;
            Qs[rr][kk] = src[(size_t)(r0 + rr) * 1024 + k0 + kk];
        }
        __syncthreads();
        for (int kk = 0; kk < 64; ++kk) {
            float w = wc[(size_t)(k0 + kk) * 1024 + n];
            #pragma unroll
            for (int r = 0; r < 4; ++r)
                acc[r] = fmaf(Qs[r][kk], w, acc[r]);
        }
    }
    float* dst = mat ? Bv : A;
    #pragma unroll
    for (int r = 0; r < 4; ++r)
        dst[(size_t)(r0 + r) * 1024 + n] = acc[r];
}

// ---------------- pair GEMM: 128x128 MFMA + fused fp32 dist + fused epilogue -----
__global__ __launch_bounds__(512, 2) void pair_gemm(
    const float* __restrict__ Q, const float* __restrict__ R,
    const float* __restrict__ Aq, const float* __restrict__ Bv,
    const int* __restrict__ nqi, const int* __restrict__ nri,
    const f16x8* __restrict__ wB,
    const float* __restrict__ w1, const float* __restrict__ b1,
    const float* __restrict__ w2, float* __restrict__ partial)
{
    int bm = blockIdx.x, bn = blockIdx.y;
    int tid = threadIdx.x, w = tid >> 6, l = tid & 63;
    __shared__ __align__(16) unsigned short As[4096];
    __shared__ float red[2048];
    __shared__ float dred[4][128];
    __shared__ int qis[128], ris[128];
    __shared__ float dsv[128];
    if (tid < 128) {
        int p = bm*128 + tid;
        int qi = (p < 128) ? p : nqi[p-128];
        int ri = (p < 128) ? p : nri[p-128];
        qis[tid] = qi; ris[tid] = ri;
    }
    __syncthreads();

    int srow = tid & 127, skg = tid >> 7;
    const float* qrow = Q + (size_t)qis[srow]*1024 + skg*8;
    const float* rrow = R + (size_t)ris[srow]*1024 + skg*8;

    float4 qa = *(const float4*)(qrow);
    float4 qb = *(const float4*)(qrow + 4);
    float4 ra = *(const float4*)(rrow);
    float4 rb = *(const float4*)(rrow + 4);

    f32x4 acc[8];
    #pragma unroll
    for (int m = 0; m < 8; ++m) acc[m] = (f32x4){0.f,0.f,0.f,0.f};
    float dacc = 0.f;

    for (int kt = 0; kt < 32; ++kt) {
        float p0 = qa.x*ra.x, p1 = qa.y*ra.y, p2 = qa.z*ra.z, p3 = qa.w*ra.w;
        float p4 = qb.x*rb.x, p5 = qb.y*rb.y, p6 = qb.z*rb.z, p7 = qb.w*rb.w;
        dacc += ((p0 + p1) + (p2 + p3)) + ((p4 + p5) + (p6 + p7));
        f16x8 prod;
        prod[0]=(_Float16)p0; prod[1]=(_Float16)p1;
        prod[2]=(_Float16)p2; prod[3]=(_Float16)p3;
        prod[4]=(_Float16)p4; prod[5]=(_Float16)p5;
        prod[6]=(_Float16)p6; prod[7]=(_Float16)p7;
        __syncthreads();
        ((f16x8*)As)[srow*4 + (skg ^ (srow & 3))] = prod;
        __syncthreads();
        if (kt + 1 < 32) {
            qa = *(const float4*)(qrow + (kt+1)*32);
            qb = *(const float4*)(qrow + (kt+1)*32 + 4);
            ra = *(const float4*)(rrow + (kt+1)*32);
            rb = *(const float4*)(rrow + (kt+1)*32 + 4);
        }
        f16x8 bf = wB[((size_t)kt*64 + bn*8 + w)*64 + l];
        #pragma unroll
        for (int mt = 0; mt < 8; ++mt) {
            f16x8 af = ((const f16x8*)As)[(mt*16 + (l & 15))*4 + ((l >> 4) ^ (l & 3))];
            acc[mt] = MFMA16(af, bf, acc[mt], 0, 0, 0);
        }
    }

    dred[skg][srow] = dacc;
    __syncthreads();
    if (tid < 128)
        dsv[tid] = (dred[0][tid] + dred[1][tid]) + (dred[2][tid] + dred[3][tid]);
    __syncthreads();

    int col = bn*128 + w*16 + (l & 15);
    float wd  = w1[(size_t)1024*1024 + col];
    float b1v = b1[col];
    float w20 = w2[col*2], w21 = w2[col*2 + 1];
    #pragma unroll
    for (int mt = 0; mt < 8; ++mt) {
        float po0[4], po1[4];
        #pragma unroll
        for (int j = 0; j < 4; ++j) {
            int lr = mt*16 + (l >> 4)*4 + j;
            float h = acc[mt][j]
                    + Aq[(size_t)qis[lr]*1024 + col]
                    + Bv[(size_t)ris[lr]*1024 + col]
                    + dsv[lr]*wd + b1v;
            h = fmaxf(h, 0.f);
            po0[j] = h * w20; po1[j] = h * w21;
        }
        #pragma unroll
        for (int s = 1; s < 16; s <<= 1) {
            #pragma unroll
            for (int j = 0; j < 4; ++j) {
                po0[j] += __shfl_xor(po0[j], s, 64);
                po1[j] += __shfl_xor(po1[j], s, 64);
            }
        }
        if ((l & 15) == 0) {
            #pragma unroll
            for (int j = 0; j < 4; ++j) {
                int row = mt*16 + (l >> 4)*4 + j;
                red[(w*128 + row)*2 + 0] = po0[j];
                red[(w*128 + row)*2 + 1] = po1[j];
            }
        }
    }
    __syncthreads();
    if (tid < 256) {
        int row = tid >> 1, cc = tid & 1;
        float s = 0.f;
        #pragma unroll
        for (int ww = 0; ww < 8; ++ww) s += red[(ww*128 + row)*2 + cc];
        partial[((size_t)bn*16384 + bm*128 + row)*2 + cc] = s;
    }
}

__global__ void final_reduce(const float* __restrict__ partial,
                             const float* __restrict__ b2, float* __restrict__ out)
{
    int gidx = blockIdx.x * 256 + threadIdx.x;
    int p = gidx >> 1, c = gidx & 1;
    float s = b2[c];
    #pragma unroll
    for (int nt = 0; nt < 8; ++nt)
        s += partial[((size_t)nt * 16384 + p) * 2 + c];
    out[gidx] = s;
}

extern "C" void kernel_launch(void* const* d_in, const int* in_sizes, int n_in,
                              void* d_out, int out_size, void* d_ws, size_t ws_size,
                              hipStream_t stream) {
    const int*   iq     = (const int*)d_in[0];
    const int*   ir     = (const int*)d_in[1];
    const int*   ql     = (const int*)d_in[2];
    const int*   rl     = (const int*)d_in[3];
    const int*   nqi    = (const int*)d_in[4];
    const int*   nri    = (const int*)d_in[5];
    const float* emb    = (const float*)d_in[6];
    const float* gate_k = (const float*)d_in[7];
    const float* gate_b = (const float*)d_in[8];
    const float* cand_k = (const float*)d_in[9];
    const float* cand_b = (const float*)d_in[10];
    const float* w1     = (const float*)d_in[11];
    const float* b1     = (const float*)d_in[12];
    const float* w2     = (const float*)d_in[13];
    const float* b2     = (const float*)d_in[14];
    float* out = (float*)d_out;
    float* ws  = (float*)d_ws;

    float* Q       = ws;                  // 131072
    float* R       = ws + 131072;         // 131072
    float* A       = ws + 262144;         // 131072
    float* Bv      = ws + 393216;         // 131072
    float* partial = ws + 540672;         // 262144
    float* gkh     = ws + 1064960;        // 8*256*512
    float* ckh     = ws + 2113536;        // 8*256*256
    f16x8* wB      = (f16x8*)(ws + 2637824);  // 131072 frags = 524288 floats
    float* wcomb   = ws + 3162112;        // 2*1024*1024 (ends 5259264 = 21.0 MB)

    conv_all<<<8192, 256, 0, stream>>>(gate_k, cand_k, w1, gkh, ckh, wB, wcomb);
    gru_encode<<<256, 1024, 0, stream>>>(iq, ir, ql, rl, emb, gkh, gate_b,
                                         ckh, cand_b, Q, R);
    ab_kernel<<<dim3(4, 32, 2), 256, 0, stream>>>(Q, R, wcomb, A, Bv);
    pair_gemm<<<dim3(128, 8), 512, 0, stream>>>(Q, R, A, Bv, nqi, nri,
                                                wB, w1, b1, w2, partial);
    final_reduce<<<128, 256, 0, stream>>>(partial, b2, out);
}